// Round 6
// baseline (340.054 us; speedup 1.0000x reference)
//
#include <hip/hip_runtime.h>
#include <math.h>

#define NEG_SLOPE 0.2f
#define BN_EPS 1e-5f

typedef __attribute__((ext_vector_type(8))) short bf16x8;
typedef __attribute__((ext_vector_type(4))) float f32x4;
typedef unsigned short u16;
typedef __attribute__((ext_vector_type(4))) unsigned short u16x4;

static __device__ __forceinline__ float leaky(float v) { return v > 0.f ? v : NEG_SLOPE * v; }
static __device__ __forceinline__ float b2f(u16 b) { return __uint_as_float(((unsigned)b) << 16); }
static __device__ __forceinline__ u16 f2b(float f) {
  unsigned u = __float_as_uint(f);
  u += 0x7FFF + ((u >> 16) & 1);
  return (u16)(u >> 16);
}
static __device__ __forceinline__ float sel4(f32x4 v, int hs) {
  float a = (hs & 1) ? v[1] : v[0];
  float b = (hs & 1) ? v[3] : v[2];
  return (hs & 2) ? b : a;
}

// ---------------- setup ----------------
__global__ void k_deg(const int* __restrict__ dst, int* __restrict__ degInt, int E) {
  int e = blockIdx.x * blockDim.x + threadIdx.x;
  if (e < E) atomicAdd(&degInt[dst[e]], 1);
}

__global__ void k_scan(const int* __restrict__ degInt, int* __restrict__ rowStart, int n) {
  __shared__ int sums[1024];
  int tid = threadIdx.x;
  int per = (n + 1023) / 1024;
  int start = tid * per;
  int end = start + per; if (end > n) end = n;
  int s = 0;
  for (int i = start; i < end; i++) s += degInt[i];
  sums[tid] = s;
  __syncthreads();
  for (int off = 1; off < 1024; off <<= 1) {
    int v = (tid >= off) ? sums[tid - off] : 0;
    __syncthreads();
    sums[tid] += v;
    __syncthreads();
  }
  int base = (tid > 0) ? sums[tid - 1] : 0;
  for (int i = start; i < end; i++) { rowStart[i] = base; base += degInt[i]; }
  if (tid == 1023) rowStart[n] = sums[1023];
}

__global__ void k_fill_csr(const int* __restrict__ src, const int* __restrict__ dst,
                           const int* __restrict__ rowStart, int* __restrict__ cursor,
                           int* __restrict__ csrSrc, int* __restrict__ csrEid,
                           int* __restrict__ posE, int E) {
  int e = blockIdx.x * blockDim.x + threadIdx.x;
  if (e >= E) return;
  int d = dst[e];
  int pos = rowStart[d] + atomicAdd(&cursor[d], 1);
  csrSrc[pos] = src[e];
  csrEid[pos] = e;
  posE[e] = pos;
}

__global__ void k_loop_gather(const int* __restrict__ rowStart, const int* __restrict__ csrEid,
                              const float* __restrict__ eattr, float* __restrict__ loopAttr, int Nn) {
  int i = blockIdx.x * blockDim.x + threadIdx.x;
  if (i >= Nn * 7) return;
  int n = i / 7, k = i % 7;
  int r0 = rowStart[n], r1 = rowStart[n + 1];
  float s = 0.f;
  for (int j = r0; j < r1; j++) s += eattr[csrEid[j] * 7 + k];
  loopAttr[i] = s / fmaxf((float)(r1 - r0), 1.0f);
}

// ---------------- casts ----------------
__global__ void k_cast_bf16(const float* __restrict__ in, u16* __restrict__ out, int n) {
  int i = blockIdx.x * blockDim.x + threadIdx.x;
  if (i < n) out[i] = f2b(in[i]);
}

__global__ void k_transpose_cast(const float* __restrict__ W, u16* __restrict__ Wt, int K, int N) {
  int i = blockIdx.x * blockDim.x + threadIdx.x;
  if (i >= K * N) return;
  int k = i / N, n = i % N;
  Wt[(size_t)n * K + k] = f2b(W[i]);
}

// ws[k][h] = sum_c W[k, h*C+c] * a_s[h,c]  (K x 4), same for wd
__global__ void k_wsd(const float* __restrict__ W, const float* __restrict__ a_s,
                      const float* __restrict__ a_d, float* __restrict__ ws,
                      float* __restrict__ wd, int K, int C) {
  int t = blockIdx.x * blockDim.x + threadIdx.x;
  if (t >= K * 4) return;
  int k = t >> 2, h = t & 3;
  float s1 = 0.f, s2 = 0.f;
  for (int c = 0; c < C; c++) {
    float w = W[(size_t)k * 4 * C + h * C + c];
    s1 += w * a_s[h * C + c];
    s2 += w * a_d[h * C + c];
  }
  ws[k * 4 + h] = s1;
  wd[k * 4 + h] = s2;
}

// ---------------- MFMA bf16 GEMM: C[M,Nc] = A[M,K] @ Bt[Nc,K]^T, optional z-batch + epilogue ----------------
template <int BM, int BN, int WM, int WN, bool EPI>
__global__ __launch_bounds__(256) void k_gemm_mfma(const u16* __restrict__ A,
                                                   const u16* __restrict__ Bt,
                                                   u16* __restrict__ Cout,
                                                   int M, int K, int Nc, int lda, int ldc,
                                                   int AzOff, int BzOff, int CzOff,
                                                   const float* __restrict__ bias,
                                                   const float* __restrict__ bng,
                                                   const float* __restrict__ bnb,
                                                   const float* __restrict__ bnrm,
                                                   const float* __restrict__ bnrv) {
  constexpr int BK = 64;
  constexpr int LDT = BK + 8;
  __shared__ u16 As[BM][LDT];
  __shared__ u16 Bs[BN][LDT];
  constexpr int NWN = BN / WN;
  constexpr int M_REP = WM / 16;
  constexpr int N_REP = WN / 16;
  int z = blockIdx.z;
  A += (size_t)z * AzOff;
  Bt += (size_t)z * BzOff;
  Cout += (size_t)z * CzOff;
  if (EPI) {
    bias += (size_t)z * CzOff; bng += (size_t)z * CzOff; bnb += (size_t)z * CzOff;
    bnrm += (size_t)z * CzOff; bnrv += (size_t)z * CzOff;
  }
  int tid = threadIdx.x;
  int wid = tid >> 6, lane = tid & 63;
  int wr = wid / NWN, wc = wid % NWN;
  int bm = blockIdx.x * BM, bn = blockIdx.y * BN;
  int l15 = lane & 15, l4 = lane >> 4;

  f32x4 acc[M_REP][N_REP];
#pragma unroll
  for (int m = 0; m < M_REP; m++)
#pragma unroll
    for (int n = 0; n < N_REP; n++) acc[m][n] = (f32x4){0.f, 0.f, 0.f, 0.f};

  for (int k0 = 0; k0 < K; k0 += BK) {
    constexpr int CHA = BM * BK / 8;
#pragma unroll
    for (int ch0 = 0; ch0 < CHA; ch0 += 256) {
      int ch = ch0 + tid;
      int row = ch >> 3, cc = (ch & 7) * 8;
      int gr = bm + row;
      bf16x8 v = {};
      if (gr < M) v = *(const bf16x8*)(A + (size_t)gr * lda + k0 + cc);
      *(bf16x8*)(&As[row][cc]) = v;
    }
    constexpr int CHB = BN * BK / 8;
#pragma unroll
    for (int ch0 = 0; ch0 < CHB; ch0 += 256) {
      int ch = ch0 + tid;
      int row = ch >> 3, cc = (ch & 7) * 8;
      int gr = bn + row;
      bf16x8 v = {};
      if (gr < Nc) v = *(const bf16x8*)(Bt + (size_t)gr * K + k0 + cc);
      *(bf16x8*)(&Bs[row][cc]) = v;
    }
    __syncthreads();
#pragma unroll
    for (int ks = 0; ks < BK; ks += 32) {
      bf16x8 af[M_REP], bfr[N_REP];
#pragma unroll
      for (int m = 0; m < M_REP; m++)
        af[m] = *(const bf16x8*)(&As[wr * WM + m * 16 + l15][ks + l4 * 8]);
#pragma unroll
      for (int n = 0; n < N_REP; n++)
        bfr[n] = *(const bf16x8*)(&Bs[wc * WN + n * 16 + l15][ks + l4 * 8]);
#pragma unroll
      for (int m = 0; m < M_REP; m++)
#pragma unroll
        for (int n = 0; n < N_REP; n++)
          acc[m][n] = __builtin_amdgcn_mfma_f32_16x16x32_bf16(af[m], bfr[n], acc[m][n], 0, 0, 0);
    }
    __syncthreads();
  }
#pragma unroll
  for (int m = 0; m < M_REP; m++) {
#pragma unroll
    for (int r = 0; r < 4; r++) {
      int grow = bm + wr * WM + m * 16 + l4 * 4 + r;
      if (grow >= M) continue;
#pragma unroll
      for (int n = 0; n < N_REP; n++) {
        int gcol = bn + wc * WN + n * 16 + l15;
        if (gcol >= Nc) continue;
        float v = acc[m][n][r];
        if (EPI) {
          v += bias[gcol];
          v = (v - bnrm[gcol]) * (bng[gcol] * rsqrtf(bnrv[gcol] + BN_EPS)) + bnb[gcol];
          v = fmaxf(v, 0.f);
        }
        Cout[(size_t)grow * ldc + gcol] = f2b(v);
      }
    }
  }
}

// ---------------- L1 attention dots from x directly: asrc = x @ ws ----------------
__global__ __launch_bounds__(256) void k_attn_x(const u16* __restrict__ xbf,
                                                const float* __restrict__ ws, const float* __restrict__ wd,
                                                float* __restrict__ asrc, float* __restrict__ adst, int Nn) {
  int n = blockIdx.x * 4 + (threadIdx.x >> 6);
  if (n >= Nn) return;
  int lane = threadIdx.x & 63;
  float xv = b2f(xbf[(size_t)n * 64 + lane]);
  f32x4 vs = *(const f32x4*)(ws + lane * 4);
  f32x4 vd = *(const f32x4*)(wd + lane * 4);
  f32x4 s1, s2;
#pragma unroll
  for (int h = 0; h < 4; h++) { s1[h] = xv * vs[h]; s2[h] = xv * vd[h]; }
#pragma unroll
  for (int off = 1; off < 64; off <<= 1) {
#pragma unroll
    for (int h = 0; h < 4; h++) { s1[h] += __shfl_xor(s1[h], off); s2[h] += __shfl_xor(s2[h], off); }
  }
  if (lane == 0) {
    *(f32x4*)(asrc + n * 4) = s1;
    *(f32x4*)(adst + n * 4) = s2;
  }
}

// attention dots post-GEMM, H=4 (L2)
template <int C, int CPL>
__global__ __launch_bounds__(256) void k_attn4(const u16* __restrict__ hbuf,
                                               const float* __restrict__ a_s, const float* __restrict__ a_d,
                                               float* __restrict__ asrc, float* __restrict__ adst, int Nn) {
  constexpr int HC = 4 * C;
  typedef __attribute__((ext_vector_type(CPL))) unsigned short u16v;
  int n = blockIdx.x * 4 + (threadIdx.x >> 6);
  if (n >= Nn) return;
  int lane = threadIdx.x & 63;
  int hs = lane >> 4, l15 = lane & 15;
  u16v hv = *(const u16v*)(hbuf + (size_t)n * HC + lane * CPL);
  float s1 = 0.f, s2 = 0.f;
#pragma unroll
  for (int jj = 0; jj < CPL; jj++) {
    float v = b2f(hv[jj]);
    int c = lane * CPL + jj;
    s1 += v * a_s[c];
    s2 += v * a_d[c];
  }
#pragma unroll
  for (int off = 1; off < 16; off <<= 1) { s1 += __shfl_xor(s1, off); s2 += __shfl_xor(s2, off); }
  if (l15 == 0) { asrc[n * 4 + hs] = s1; adst[n * 4 + hs] = s2; }
}

// generic (L3, H=1, C=32)
__global__ __launch_bounds__(256) void k_attn_nd(const u16* __restrict__ hbuf,
                                                 const float* __restrict__ a_s, const float* __restrict__ a_d,
                                                 float* __restrict__ asrc, float* __restrict__ adst,
                                                 int total, int H, int C) {
  int idx = blockIdx.x * 4 + (threadIdx.x >> 6);
  if (idx >= total) return;
  int n = idx / H, h = idx % H;
  int lane = threadIdx.x & 63;
  float s1 = 0.f, s2 = 0.f;
  for (int c = lane; c < C; c += 64) {
    float v = b2f(hbuf[(size_t)n * H * C + h * C + c]);
    s1 += v * a_s[h * C + c];
    s2 += v * a_d[h * C + c];
  }
  for (int off = 32; off > 0; off >>= 1) { s1 += __shfl_xor(s1, off); s2 += __shfl_xor(s2, off); }
  if (lane == 0) { asrc[idx] = s1; adst[idx] = s2; }
}

__global__ void k_watt(const float* __restrict__ We, const float* __restrict__ a_e,
                       float* __restrict__ w_att, int H, int C) {
  int t = threadIdx.x;
  if (t >= 7 * H) return;
  int d = t / H, h = t % H;
  float s = 0.f;
  for (int c = 0; c < C; c++) s += We[(size_t)d * H * C + h * C + c] * a_e[h * C + c];
  w_att[d * H + h] = s;
}

template <int H>
__global__ void k_edge_logit(const int* __restrict__ src, const int* __restrict__ dst,
                             const float* __restrict__ eattr, const int* __restrict__ posE,
                             const float* __restrict__ asrc, const float* __restrict__ adst,
                             const float* __restrict__ w_att, float* __restrict__ logitC, int E) {
  int e = blockIdx.x * blockDim.x + threadIdx.x;
  if (e >= E) return;
  float ea[7];
#pragma unroll
  for (int d = 0; d < 7; d++) ea[d] = eattr[e * 7 + d];
  int s = src[e], dn = dst[e];
  int pos = posE[e];
  if (H == 4) {
    f32x4 va = *(const f32x4*)(asrc + s * 4);
    f32x4 vd = *(const f32x4*)(adst + dn * 4);
    f32x4 o;
#pragma unroll
    for (int h = 0; h < 4; h++) {
      float ae = 0.f;
#pragma unroll
      for (int d = 0; d < 7; d++) ae += ea[d] * w_att[d * 4 + h];
      o[h] = leaky(va[h] + vd[h] + ae);
    }
    *(f32x4*)(logitC + (size_t)pos * 4) = o;
  } else {
    float ae = 0.f;
#pragma unroll
    for (int d = 0; d < 7; d++) ae += ea[d] * w_att[d];
    logitC[pos] = leaky(asrc[s] + adst[dn] + ae);
  }
}

// ---------------- L1 gather in x-space: agg[n][h][k] = sum alpha_h * x[src][k] ----------------
__global__ __launch_bounds__(256) void k_gather_x(
    const int* __restrict__ rowStart, const int* __restrict__ csrSrc,
    const float* __restrict__ logitC, const float* __restrict__ loopAttr,
    const float* __restrict__ w_att, const float* __restrict__ asrc, const float* __restrict__ adst,
    const u16* __restrict__ xbf, u16* __restrict__ aggOut, int Nn) {
  int wid = threadIdx.x >> 6;
  int n = blockIdx.x * 4 + wid;
  if (n >= Nn) return;
  int lane = threadIdx.x & 63;
  __shared__ float pbuf[4][64 * 4];
  int r0 = rowStart[n], r1 = rowStart[n + 1];

  f32x4 va = *(const f32x4*)(asrc + n * 4);
  f32x4 vd = *(const f32x4*)(adst + n * 4);
  float la[7];
#pragma unroll
  for (int d = 0; d < 7; d++) la[d] = loopAttr[n * 7 + d];
  f32x4 ls;
#pragma unroll
  for (int h = 0; h < 4; h++) {
    float ae = 0.f;
#pragma unroll
    for (int d = 0; d < 7; d++) ae += la[d] * w_att[d * 4 + h];
    ls[h] = leaky(va[h] + vd[h] + ae);
  }

  f32x4 m = ls;
  f32x4 denl = {0.f, 0.f, 0.f, 0.f};
  f32x4 acc = {0.f, 0.f, 0.f, 0.f};  // per-head accumulation of this lane's x column

  const f32x4* L4 = (const f32x4*)logitC;
  for (int base = r0; base < r1; base += 64) {
    int slot = base + lane;
    bool valid = slot < r1;
    f32x4 lg = valid ? L4[slot] : (f32x4){-1e30f, -1e30f, -1e30f, -1e30f};
    int srcl = valid ? csrSrc[slot] : 0;
    f32x4 mc = lg;
#pragma unroll
    for (int off = 1; off < 64; off <<= 1) {
#pragma unroll
      for (int h = 0; h < 4; h++) mc[h] = fmaxf(mc[h], __shfl_xor(mc[h], off));
    }
    f32x4 rr;
#pragma unroll
    for (int h = 0; h < 4; h++) {
      float mn = fmaxf(m[h], mc[h]);
      rr[h] = __expf(m[h] - mn);
      m[h] = mn;
      denl[h] *= rr[h];
      acc[h] *= rr[h];
    }
    f32x4 ex;
#pragma unroll
    for (int h = 0; h < 4; h++) ex[h] = valid ? __expf(lg[h] - m[h]) : 0.f;
#pragma unroll
    for (int h = 0; h < 4; h++) denl[h] += ex[h];
    *(f32x4*)(&pbuf[wid][lane * 4]) = ex;
    int nv = r1 - base; if (nv > 64) nv = 64;
    int j = 0;
    for (; j + 1 < nv; j += 2) {
      int s0 = __shfl(srcl, j);
      int s1 = __shfl(srcl, j + 1);
      f32x4 p0 = *(const f32x4*)(&pbuf[wid][j * 4]);
      f32x4 p1 = *(const f32x4*)(&pbuf[wid][(j + 1) * 4]);
      float x0 = b2f(xbf[(size_t)s0 * 64 + lane]);
      float x1 = b2f(xbf[(size_t)s1 * 64 + lane]);
#pragma unroll
      for (int h = 0; h < 4; h++) acc[h] += p0[h] * x0 + p1[h] * x1;
    }
    if (j < nv) {
      int s0 = __shfl(srcl, j);
      f32x4 p0 = *(const f32x4*)(&pbuf[wid][j * 4]);
      float x0 = b2f(xbf[(size_t)s0 * 64 + lane]);
#pragma unroll
      for (int h = 0; h < 4; h++) acc[h] += p0[h] * x0;
    }
  }
  // self loop + final reduce
  f32x4 exs;
#pragma unroll
  for (int h = 0; h < 4; h++) exs[h] = __expf(ls[h] - m[h]);
  f32x4 den;
#pragma unroll
  for (int h = 0; h < 4; h++) {
    float v = denl[h];
#pragma unroll
    for (int off = 1; off < 64; off <<= 1) v += __shfl_xor(v, off);
    den[h] = v + exs[h];
  }
  {
    float xn = b2f(xbf[(size_t)n * 64 + lane]);
#pragma unroll
    for (int h = 0; h < 4; h++) acc[h] += exs[h] * xn;
  }
  // transpose via LDS (wave-private region) -> coalesced 8B stores
#pragma unroll
  for (int h = 0; h < 4; h++) pbuf[wid][h * 64 + lane] = acc[h] / den[h];
  u16x4 ov;
#pragma unroll
  for (int jj = 0; jj < 4; jj++) ov[jj] = f2b(pbuf[wid][lane * 4 + jj]);
  *(u16x4*)(aggOut + (size_t)n * 256 + lane * 4) = ov;
}

// ---------------- gather (H=4) post-GEMM: online softmax, CSR-sequential logits ----------------
template <int C, int CPL>
__global__ __launch_bounds__(256) void k_gather4(
    const int* __restrict__ rowStart, const int* __restrict__ csrSrc,
    const float* __restrict__ logitC, const float* __restrict__ loopAttr,
    const float* __restrict__ w_att, const float* __restrict__ asrc, const float* __restrict__ adst,
    const u16* __restrict__ hbuf, const float* __restrict__ bias,
    const float* __restrict__ bng, const float* __restrict__ bnb,
    const float* __restrict__ bnrm, const float* __restrict__ bnrv,
    u16* __restrict__ outbuf, int Nn) {
  constexpr int HC = 4 * C;
  typedef __attribute__((ext_vector_type(CPL))) unsigned short u16v;
  int wid = threadIdx.x >> 6;
  int n = blockIdx.x * 4 + wid;
  if (n >= Nn) return;
  int lane = threadIdx.x & 63;
  int hs = lane >> 4;
  __shared__ float pbuf[4][64 * 4];
  int r0 = rowStart[n], r1 = rowStart[n + 1];

  f32x4 va = *(const f32x4*)(asrc + n * 4);
  f32x4 vd = *(const f32x4*)(adst + n * 4);
  float la[7];
#pragma unroll
  for (int d = 0; d < 7; d++) la[d] = loopAttr[n * 7 + d];
  f32x4 ls;
#pragma unroll
  for (int h = 0; h < 4; h++) {
    float ae = 0.f;
#pragma unroll
    for (int d = 0; d < 7; d++) ae += la[d] * w_att[d * 4 + h];
    ls[h] = leaky(va[h] + vd[h] + ae);
  }

  f32x4 m = ls;
  f32x4 denl = {0.f, 0.f, 0.f, 0.f};
  float acc[CPL];
#pragma unroll
  for (int jj = 0; jj < CPL; jj++) acc[jj] = 0.f;

  const f32x4* L4 = (const f32x4*)logitC;
  for (int base = r0; base < r1; base += 64) {
    int slot = base + lane;
    bool valid = slot < r1;
    f32x4 lg = valid ? L4[slot] : (f32x4){-1e30f, -1e30f, -1e30f, -1e30f};
    int srcl = valid ? csrSrc[slot] : 0;
    f32x4 mc = lg;
#pragma unroll
    for (int off = 1; off < 64; off <<= 1) {
#pragma unroll
      for (int h = 0; h < 4; h++) mc[h] = fmaxf(mc[h], __shfl_xor(mc[h], off));
    }
    f32x4 rr;
#pragma unroll
    for (int h = 0; h < 4; h++) {
      float mn = fmaxf(m[h], mc[h]);
      rr[h] = __expf(m[h] - mn);
      m[h] = mn;
      denl[h] *= rr[h];
    }
    float rrh = sel4(rr, hs);
#pragma unroll
    for (int jj = 0; jj < CPL; jj++) acc[jj] *= rrh;
    f32x4 ex;
#pragma unroll
    for (int h = 0; h < 4; h++) ex[h] = valid ? __expf(lg[h] - m[h]) : 0.f;
#pragma unroll
    for (int h = 0; h < 4; h++) denl[h] += ex[h];
    *(f32x4*)(&pbuf[wid][lane * 4]) = ex;
    int nv = r1 - base; if (nv > 64) nv = 64;
    int j = 0;
    for (; j + 1 < nv; j += 2) {
      int s0 = __shfl(srcl, j);
      int s1 = __shfl(srcl, j + 1);
      float p0 = pbuf[wid][j * 4 + hs];
      float p1 = pbuf[wid][(j + 1) * 4 + hs];
      u16v h0 = *(const u16v*)(hbuf + (size_t)s0 * HC + lane * CPL);
      u16v h1 = *(const u16v*)(hbuf + (size_t)s1 * HC + lane * CPL);
#pragma unroll
      for (int jj = 0; jj < CPL; jj++) acc[jj] += p0 * b2f(h0[jj]) + p1 * b2f(h1[jj]);
    }
    if (j < nv) {
      int s0 = __shfl(srcl, j);
      float p0 = pbuf[wid][j * 4 + hs];
      u16v h0 = *(const u16v*)(hbuf + (size_t)s0 * HC + lane * CPL);
#pragma unroll
      for (int jj = 0; jj < CPL; jj++) acc[jj] += p0 * b2f(h0[jj]);
    }
  }
  f32x4 exs;
#pragma unroll
  for (int h = 0; h < 4; h++) exs[h] = __expf(ls[h] - m[h]);
  f32x4 den;
#pragma unroll
  for (int h = 0; h < 4; h++) {
    float v = denl[h];
#pragma unroll
    for (int off = 1; off < 64; off <<= 1) v += __shfl_xor(v, off);
    den[h] = v + exs[h];
  }
  {
    float ps = sel4(exs, hs);
    u16v hN = *(const u16v*)(hbuf + (size_t)n * HC + lane * CPL);
#pragma unroll
    for (int jj = 0; jj < CPL; jj++) acc[jj] += ps * b2f(hN[jj]);
  }
  float dh = sel4(den, hs);
  u16v ov;
#pragma unroll
  for (int jj = 0; jj < CPL; jj++) {
    int c = lane * CPL + jj;
    float v = acc[jj] / dh + bias[c];
    v = (v - bnrm[c]) * (bng[c] * rsqrtf(bnrv[c] + BN_EPS)) + bnb[c];
    ov[jj] = f2b(fmaxf(v, 0.f));
  }
  *(u16v*)(outbuf + (size_t)n * HC + lane * CPL) = ov;
}

// ---------------- gather (H=1, C=32) ----------------
__global__ __launch_bounds__(256) void k_gather_L3(
    const int* __restrict__ rowStart, const int* __restrict__ csrSrc,
    const float* __restrict__ logitC, const float* __restrict__ loopAttr,
    const float* __restrict__ w_att, const float* __restrict__ asrc, const float* __restrict__ adst,
    const u16* __restrict__ hbuf, const float* __restrict__ bias,
    const float* __restrict__ bng, const float* __restrict__ bnb,
    const float* __restrict__ bnrm, const float* __restrict__ bnrv,
    u16* __restrict__ outbuf, int Nn) {
  int n = blockIdx.x * 4 + (threadIdx.x >> 6);
  if (n >= Nn) return;
  int lane = threadIdx.x & 63;
  int cl = lane & 31, half = lane >> 5;
  int r0 = rowStart[n], r1 = rowStart[n + 1];
  float ae = 0.f;
#pragma unroll
  for (int d = 0; d < 7; d++) ae += loopAttr[n * 7 + d] * w_att[d];
  float ls = leaky(asrc[n] + adst[n] + ae);

  float m = ls;
  for (int j = r0 + lane; j < r1; j += 64) m = fmaxf(m, logitC[j]);
  for (int off = 32; off > 0; off >>= 1) m = fmaxf(m, __shfl_xor(m, off));
  float den = 0.f;
  for (int j = r0 + lane; j < r1; j += 64) den += __expf(logitC[j] - m);
  for (int off = 32; off > 0; off >>= 1) den += __shfl_xor(den, off);
  den += __expf(ls - m);

  float acc = 0.f;
  for (int j = r0 + half; j < r1; j += 2) {
    float p = __expf(logitC[j] - m);
    int s = csrSrc[j];
    acc += p * b2f(hbuf[(size_t)s * 32 + cl]);
  }
  if (half == 0) acc += __expf(ls - m) * b2f(hbuf[(size_t)n * 32 + cl]);
  acc += __shfl_xor(acc, 32);
  if (half == 0) {
    float v = acc / den + bias[cl];
    v = (v - bnrm[cl]) * (bng[cl] * rsqrtf(bnrv[cl] + BN_EPS)) + bnb[cl];
    outbuf[(size_t)n * 32 + cl] = f2b(fmaxf(v, 0.f));
  }
}

// ---------------- fused pooling + MLP ----------------
__global__ __launch_bounds__(256) void k_pool_mlp(
    const u16* __restrict__ h3, const int* __restrict__ batch, int Nn,
    const float* __restrict__ lw1, const float* __restrict__ lb1,
    const float* __restrict__ lw2, const float* __restrict__ lb2,
    float* __restrict__ out) {
  int g = blockIdx.x;
  int tid = threadIdx.x;
  __shared__ int s_lo, s_hi;
  if (tid == 0) {
    int lo = 0, hi = Nn;
    while (lo < hi) { int mid = (lo + hi) >> 1; if (batch[mid] < g) lo = mid + 1; else hi = mid; }
    s_lo = lo;
    int lo2 = lo, hi2 = Nn;
    while (lo2 < hi2) { int mid = (lo2 + hi2) >> 1; if (batch[mid] < g + 1) lo2 = mid + 1; else hi2 = mid; }
    s_hi = lo2;
  }
  __syncthreads();
  int lo = s_lo, hi = s_hi;
  int c = tid & 31, r = tid >> 5;
  float sum = 0.f, mx = -1e30f;
  for (int n = lo + r; n < hi; n += 8) {
    float v = b2f(h3[(size_t)n * 32 + c]);
    sum += v;
    mx = fmaxf(mx, v);
  }
  __shared__ float ssum[8][32];
  __shared__ float smax[8][32];
  ssum[r][c] = sum;
  smax[r][c] = mx;
  __syncthreads();
  __shared__ float z[64];
  __shared__ float zz1[32];
  if (tid < 32) {
    float s = 0.f, m2 = -1e30f;
#pragma unroll
    for (int rr = 0; rr < 8; rr++) { s += ssum[rr][tid]; m2 = fmaxf(m2, smax[rr][tid]); }
    int cnt = hi - lo;
    z[tid] = s / fmaxf((float)cnt, 1.0f);
    z[32 + tid] = (cnt > 0) ? m2 : 0.f;
  }
  __syncthreads();
  if (tid < 32) {
    float s = lb1[tid];
    for (int k = 0; k < 64; k++) s += z[k] * lw1[k * 32 + tid];
    zz1[tid] = fmaxf(s, 0.f);
  }
  __syncthreads();
  if (tid == 0) {
    float s = lb2[0];
    for (int j = 0; j < 32; j++) s += zz1[j] * lw2[j];
    out[g] = 1.f / (1.f + expf(-s));
  }
}

// ---------------- driver ----------------
extern "C" void kernel_launch(void* const* d_in, const int* in_sizes, int n_in,
                              void* d_out, int out_size, void* d_ws, size_t ws_size,
                              hipStream_t stream) {
  const float* x     = (const float*)d_in[0];
  const int*   eidx  = (const int*)d_in[1];
  const float* eattr = (const float*)d_in[2];
  const int*   batch = (const int*)d_in[3];
  int N = in_sizes[0] / 64;
  int E = in_sizes[1] / 2;
  int NG = out_size;
  const int* src = eidx;
  const int* dst = eidx + E;

  const float* W[3]  = {(const float*)d_in[4],  (const float*)d_in[14], (const float*)d_in[24]};
  const float* AS[3] = {(const float*)d_in[5],  (const float*)d_in[15], (const float*)d_in[25]};
  const float* AD[3] = {(const float*)d_in[6],  (const float*)d_in[16], (const float*)d_in[26]};
  const float* WE[3] = {(const float*)d_in[7],  (const float*)d_in[17], (const float*)d_in[27]};
  const float* AE[3] = {(const float*)d_in[8],  (const float*)d_in[18], (const float*)d_in[28]};
  const float* B[3]  = {(const float*)d_in[9],  (const float*)d_in[19], (const float*)d_in[29]};
  const float* G[3]  = {(const float*)d_in[10], (const float*)d_in[20], (const float*)d_in[30]};
  const float* BT[3] = {(const float*)d_in[11], (const float*)d_in[21], (const float*)d_in[31]};
  const float* RM[3] = {(const float*)d_in[12], (const float*)d_in[22], (const float*)d_in[32]};
  const float* RV[3] = {(const float*)d_in[13], (const float*)d_in[23], (const float*)d_in[33]};
  const float* lw1 = (const float*)d_in[34];
  const float* lb1 = (const float*)d_in[35];
  const float* lw2 = (const float*)d_in[36];
  const float* lb2 = (const float*)d_in[37];

  char* wp = (char*)d_ws;
  auto alloc = [&](size_t bytes) -> void* {
    void* p = (void*)wp;
    wp += (bytes + 255) & ~(size_t)255;
    return p;
  };
  u16*   xbf      = (u16*)alloc((size_t)N * 64 * 2);
  u16*   aggB     = (u16*)alloc((size_t)N * 256 * 2);
  u16*   bufH     = (u16*)alloc((size_t)N * 512 * 2);
  u16*   bufA     = (u16*)alloc((size_t)N * 512 * 2);
  u16*   Wt1      = (u16*)alloc((size_t)512 * 64 * 2);
  u16*   Wt2      = (u16*)alloc((size_t)256 * 512 * 2);
  u16*   Wt3      = (u16*)alloc((size_t)32 * 256 * 2);
  int*   degInt   = (int*)alloc((size_t)N * 4);
  int*   cursor   = (int*)alloc((size_t)N * 4);
  int*   rowStart = (int*)alloc((size_t)(N + 1) * 4);
  float* loopAttr = (float*)alloc((size_t)N * 7 * 4);
  int*   csrSrc   = (int*)alloc((size_t)E * 4);
  int*   csrEid   = (int*)alloc((size_t)E * 4);
  int*   posE     = (int*)alloc((size_t)E * 4);
  float* logitC   = (float*)alloc((size_t)E * 4 * 4);
  float* asrc     = (float*)alloc((size_t)N * 4 * 4);
  float* adst     = (float*)alloc((size_t)N * 4 * 4);
  float* watt     = (float*)alloc(32 * 4);
  float* ws1      = (float*)alloc(64 * 4 * 4);
  float* wd1      = (float*)alloc(64 * 4 * 4);

  hipMemsetAsync(degInt, 0, (size_t)N * 4, stream);
  hipMemsetAsync(cursor, 0, (size_t)N * 4, stream);

  // setup
  k_deg<<<(E + 255) / 256, 256, 0, stream>>>(dst, degInt, E);
  k_scan<<<1, 1024, 0, stream>>>(degInt, rowStart, N);
  k_fill_csr<<<(E + 255) / 256, 256, 0, stream>>>(src, dst, rowStart, cursor, csrSrc, csrEid, posE, E);
  k_loop_gather<<<(N * 7 + 255) / 256, 256, 0, stream>>>(rowStart, csrEid, eattr, loopAttr, N);
  k_cast_bf16<<<(N * 64 + 255) / 256, 256, 0, stream>>>(x, xbf, N * 64);
  k_transpose_cast<<<(64 * 512 + 255) / 256, 256, 0, stream>>>(W[0], Wt1, 64, 512);
  k_transpose_cast<<<(512 * 256 + 255) / 256, 256, 0, stream>>>(W[1], Wt2, 512, 256);
  k_transpose_cast<<<(256 * 32 + 255) / 256, 256, 0, stream>>>(W[2], Wt3, 256, 32);
  k_wsd<<<1, 256, 0, stream>>>(W[0], AS[0], AD[0], ws1, wd1, 64, 128);

  int gmM = (N + 127) / 128;
  int nb4 = (N + 3) / 4;

  // ---- layer 1: aggregate in x-space (64-dim), then 4 head-GEMMs [N,64]@[64,128] + epilogue
  k_attn_x<<<nb4, 256, 0, stream>>>(xbf, ws1, wd1, asrc, adst, N);
  k_watt<<<1, 64, 0, stream>>>(WE[0], AE[0], watt, 4, 128);
  k_edge_logit<4><<<(E + 255) / 256, 256, 0, stream>>>(src, dst, eattr, posE, asrc, adst, watt, logitC, E);
  k_gather_x<<<nb4, 256, 0, stream>>>(rowStart, csrSrc, logitC, loopAttr, watt, asrc, adst, xbf, aggB, N);
  k_gemm_mfma<128, 128, 64, 64, true><<<dim3(gmM, 1, 4), 256, 0, stream>>>(
      aggB, Wt1, bufA, N, 64, 128, 256, 512, 64, 128 * 64, 128,
      B[0], G[0], BT[0], RM[0], RV[0]);

  // ---- layer 2: K=512, H=4, C=64, HC=256 (post-GEMM aggregation, 512B rows)
  k_gemm_mfma<128, 128, 64, 64, false><<<dim3(gmM, 2, 1), 256, 0, stream>>>(
      bufA, Wt2, bufH, N, 512, 256, 512, 256, 0, 0, 0,
      nullptr, nullptr, nullptr, nullptr, nullptr);
  k_attn4<64, 4><<<nb4, 256, 0, stream>>>(bufH, AS[1], AD[1], asrc, adst, N);
  k_watt<<<1, 64, 0, stream>>>(WE[1], AE[1], watt, 4, 64);
  k_edge_logit<4><<<(E + 255) / 256, 256, 0, stream>>>(src, dst, eattr, posE, asrc, adst, watt, logitC, E);
  k_gather4<64, 4><<<nb4, 256, 0, stream>>>(rowStart, csrSrc, logitC, loopAttr, watt, asrc, adst,
                                            bufH, B[1], G[1], BT[1], RM[1], RV[1], bufA, N);

  // ---- layer 3: K=256, H=1, C=32
  k_gemm_mfma<128, 32, 32, 32, false><<<dim3(gmM, 1, 1), 256, 0, stream>>>(
      bufA, Wt3, bufH, N, 256, 32, 256, 32, 0, 0, 0,
      nullptr, nullptr, nullptr, nullptr, nullptr);
  k_attn_nd<<<(N + 3) / 4, 256, 0, stream>>>(bufH, AS[2], AD[2], asrc, adst, N, 1, 32);
  k_watt<<<1, 64, 0, stream>>>(WE[2], AE[2], watt, 1, 32);
  k_edge_logit<1><<<(E + 255) / 256, 256, 0, stream>>>(src, dst, eattr, posE, asrc, adst, watt, logitC, E);
  k_gather_L3<<<nb4, 256, 0, stream>>>(rowStart, csrSrc, logitC, loopAttr, watt, asrc, adst,
                                       bufH, B[2], G[2], BT[2], RM[2], RV[2], bufA, N);

  // ---- fused pooling + MLP
  k_pool_mlp<<<NG, 256, 0, stream>>>(bufA, batch, N, lw1, lb1, lw2, lb2, (float*)d_out);
}

// Round 7
// 285.916 us; speedup vs baseline: 1.1893x; 1.1893x over previous
//
#include <hip/hip_runtime.h>
#include <math.h>

#define NEG_SLOPE 0.2f
#define BN_EPS 1e-5f

typedef __attribute__((ext_vector_type(8))) short bf16x8;
typedef __attribute__((ext_vector_type(4))) float f32x4;
typedef unsigned short u16;
typedef __attribute__((ext_vector_type(4))) unsigned short u16x4;

static __device__ __forceinline__ float leaky(float v) { return v > 0.f ? v : NEG_SLOPE * v; }
static __device__ __forceinline__ float b2f(u16 b) { return __uint_as_float(((unsigned)b) << 16); }
static __device__ __forceinline__ u16 f2b(float f) {
  unsigned u = __float_as_uint(f);
  u += 0x7FFF + ((u >> 16) & 1);
  return (u16)(u >> 16);
}
static __device__ __forceinline__ float sel4(f32x4 v, int hs) {
  float a = (hs & 1) ? v[1] : v[0];
  float b = (hs & 1) ? v[3] : v[2];
  return (hs & 2) ? b : a;
}

// ---------------- fused prep: weight transposes + attn-weight projections + zero deg/cursor ----------------
__global__ void k_prep(const float* __restrict__ W1, const float* __restrict__ W2, const float* __restrict__ W3,
                       const float* __restrict__ AS1, const float* __restrict__ AD1,
                       const float* __restrict__ WE1, const float* __restrict__ AE1,
                       const float* __restrict__ WE2, const float* __restrict__ AE2,
                       const float* __restrict__ WE3, const float* __restrict__ AE3,
                       u16* __restrict__ Wt1, u16* __restrict__ Wt2, u16* __restrict__ Wt3,
                       float* __restrict__ ws1, float* __restrict__ wd1,
                       float* __restrict__ watt1, float* __restrict__ watt2, float* __restrict__ watt3,
                       int* __restrict__ degInt, int* __restrict__ cursor, int Nn) {
  int idx = blockIdx.x * blockDim.x + threadIdx.x;
  if (idx < 32768) {                       // Wt1 [512][64] <- W1 [64][512]
    int k = idx >> 9, n = idx & 511;
    Wt1[n * 64 + k] = f2b(W1[idx]);
  } else if (idx < 163840) {               // Wt2 [256][512] <- W2 [512][256]
    int i = idx - 32768;
    int k = i >> 8, n = i & 255;
    Wt2[n * 512 + k] = f2b(W2[i]);
  } else if (idx < 172032) {               // Wt3 [32][256] <- W3 [256][32]
    int i = idx - 163840;
    int k = i >> 5, n = i & 31;
    Wt3[n * 256 + k] = f2b(W3[i]);
  } else if (idx < 172288) {               // ws1/wd1 [64][4]
    int t = idx - 172032;
    int k = t >> 2, h = t & 3;
    float s1 = 0.f, s2 = 0.f;
    for (int c = 0; c < 128; c++) {
      float w = W1[k * 512 + h * 128 + c];
      s1 += w * AS1[h * 128 + c];
      s2 += w * AD1[h * 128 + c];
    }
    ws1[t] = s1; wd1[t] = s2;
  } else if (idx < 172316) {               // watt1 [7][4]
    int t = idx - 172288;
    int d = t >> 2, h = t & 3;
    float s = 0.f;
    for (int c = 0; c < 128; c++) s += WE1[d * 512 + h * 128 + c] * AE1[h * 128 + c];
    watt1[t] = s;
  } else if (idx < 172344) {               // watt2 [7][4]
    int t = idx - 172316;
    int d = t >> 2, h = t & 3;
    float s = 0.f;
    for (int c = 0; c < 64; c++) s += WE2[d * 256 + h * 64 + c] * AE2[h * 64 + c];
    watt2[t] = s;
  } else if (idx < 172351) {               // watt3 [7]
    int d = idx - 172344;
    float s = 0.f;
    for (int c = 0; c < 32; c++) s += WE3[d * 32 + c] * AE3[c];
    watt3[d] = s;
  } else if (idx >= 172352 && idx < 172352 + Nn) {
    degInt[idx - 172352] = 0;
  } else if (idx >= 172352 + Nn && idx < 172352 + 2 * Nn) {
    cursor[idx - 172352 - Nn] = 0;
  }
}

// ---------------- setup ----------------
__global__ void k_deg(const int* __restrict__ dst, int* __restrict__ degInt, int E) {
  int e = blockIdx.x * blockDim.x + threadIdx.x;
  if (e < E) atomicAdd(&degInt[dst[e]], 1);
}

__global__ void k_scan(const int* __restrict__ degInt, int* __restrict__ rowStart, int n) {
  __shared__ int sums[1024];
  int tid = threadIdx.x;
  int per = (n + 1023) / 1024;
  int start = tid * per;
  int end = start + per; if (end > n) end = n;
  int s = 0;
  for (int i = start; i < end; i++) s += degInt[i];
  sums[tid] = s;
  __syncthreads();
  for (int off = 1; off < 1024; off <<= 1) {
    int v = (tid >= off) ? sums[tid - off] : 0;
    __syncthreads();
    sums[tid] += v;
    __syncthreads();
  }
  int base = (tid > 0) ? sums[tid - 1] : 0;
  for (int i = start; i < end; i++) { rowStart[i] = base; base += degInt[i]; }
  if (tid == 1023) rowStart[n] = sums[1023];
}

__global__ void k_fill_csr(const int* __restrict__ src, const int* __restrict__ dst,
                           const int* __restrict__ rowStart, int* __restrict__ cursor,
                           int* __restrict__ csrSrc, int* __restrict__ csrEid,
                           int* __restrict__ posE, int E) {
  int e = blockIdx.x * blockDim.x + threadIdx.x;
  if (e >= E) return;
  int d = dst[e];
  int pos = rowStart[d] + atomicAdd(&cursor[d], 1);
  csrSrc[pos] = src[e];
  csrEid[pos] = e;
  posE[e] = pos;
}

__global__ void k_loop_gather(const int* __restrict__ rowStart, const int* __restrict__ csrEid,
                              const float* __restrict__ eattr, float* __restrict__ loopAttr, int Nn) {
  int i = blockIdx.x * blockDim.x + threadIdx.x;
  if (i >= Nn * 7) return;
  int n = i / 7, k = i % 7;
  int r0 = rowStart[n], r1 = rowStart[n + 1];
  float s = 0.f;
  for (int j = r0; j < r1; j++) s += eattr[csrEid[j] * 7 + k];
  loopAttr[i] = s / fmaxf((float)(r1 - r0), 1.0f);
}

// ---------------- fused x cast + L1 attention dots ----------------
__global__ __launch_bounds__(256) void k_cast_attn_x(const float* __restrict__ x, u16* __restrict__ xbf,
                                                     const float* __restrict__ ws, const float* __restrict__ wd,
                                                     float* __restrict__ asrc, float* __restrict__ adst, int Nn) {
  int n = blockIdx.x * 4 + (threadIdx.x >> 6);
  if (n >= Nn) return;
  int lane = threadIdx.x & 63;
  float xv = x[(size_t)n * 64 + lane];
  xbf[(size_t)n * 64 + lane] = f2b(xv);
  f32x4 vs = *(const f32x4*)(ws + lane * 4);
  f32x4 vd = *(const f32x4*)(wd + lane * 4);
  f32x4 s1, s2;
#pragma unroll
  for (int h = 0; h < 4; h++) { s1[h] = xv * vs[h]; s2[h] = xv * vd[h]; }
#pragma unroll
  for (int off = 1; off < 64; off <<= 1) {
#pragma unroll
    for (int h = 0; h < 4; h++) { s1[h] += __shfl_xor(s1[h], off); s2[h] += __shfl_xor(s2[h], off); }
  }
  if (lane == 0) {
    *(f32x4*)(asrc + n * 4) = s1;
    *(f32x4*)(adst + n * 4) = s2;
  }
}

// ---------------- MFMA bf16 GEMM with optional epilogue / fused attn dots ----------------
// ATTN_H>0 requires WN == per-head C; head = blockIdx.y*NWN + wc.
template <int BM, int BN, int WM, int WN, bool EPI, int ATTN_H>
__global__ __launch_bounds__(256) void k_gemm_mfma(const u16* __restrict__ A,
                                                   const u16* __restrict__ Bt,
                                                   u16* __restrict__ Cout,
                                                   int M, int K, int Nc, int lda, int ldc,
                                                   int AzOff, int BzOff, int CzOff,
                                                   const float* __restrict__ bias,
                                                   const float* __restrict__ bng,
                                                   const float* __restrict__ bnb,
                                                   const float* __restrict__ bnrm,
                                                   const float* __restrict__ bnrv,
                                                   const float* __restrict__ a_s,
                                                   const float* __restrict__ a_d,
                                                   float* __restrict__ asrc,
                                                   float* __restrict__ adst) {
  constexpr int BK = 64;
  constexpr int LDT = BK + 8;
  __shared__ u16 As[BM][LDT];
  __shared__ u16 Bs[BN][LDT];
  constexpr int NWN = BN / WN;
  constexpr int M_REP = WM / 16;
  constexpr int N_REP = WN / 16;
  int z = blockIdx.z;
  A += (size_t)z * AzOff;
  Bt += (size_t)z * BzOff;
  Cout += (size_t)z * CzOff;
  if (EPI) {
    bias += (size_t)z * CzOff; bng += (size_t)z * CzOff; bnb += (size_t)z * CzOff;
    bnrm += (size_t)z * CzOff; bnrv += (size_t)z * CzOff;
  }
  int tid = threadIdx.x;
  int wid = tid >> 6, lane = tid & 63;
  int wr = wid / NWN, wc = wid % NWN;
  int bm = blockIdx.x * BM, bn = blockIdx.y * BN;
  int l15 = lane & 15, l4 = lane >> 4;

  f32x4 acc[M_REP][N_REP];
#pragma unroll
  for (int m = 0; m < M_REP; m++)
#pragma unroll
    for (int n = 0; n < N_REP; n++) acc[m][n] = (f32x4){0.f, 0.f, 0.f, 0.f};

  for (int k0 = 0; k0 < K; k0 += BK) {
    constexpr int CHA = BM * BK / 8;
#pragma unroll
    for (int ch0 = 0; ch0 < CHA; ch0 += 256) {
      int ch = ch0 + tid;
      int row = ch >> 3, cc = (ch & 7) * 8;
      int gr = bm + row;
      bf16x8 v = {};
      if (gr < M) v = *(const bf16x8*)(A + (size_t)gr * lda + k0 + cc);
      *(bf16x8*)(&As[row][cc]) = v;
    }
    constexpr int CHB = BN * BK / 8;
#pragma unroll
    for (int ch0 = 0; ch0 < CHB; ch0 += 256) {
      int ch = ch0 + tid;
      int row = ch >> 3, cc = (ch & 7) * 8;
      int gr = bn + row;
      bf16x8 v = {};
      if (gr < Nc) v = *(const bf16x8*)(Bt + (size_t)gr * K + k0 + cc);
      *(bf16x8*)(&Bs[row][cc]) = v;
    }
    __syncthreads();
#pragma unroll
    for (int ks = 0; ks < BK; ks += 32) {
      bf16x8 af[M_REP], bfr[N_REP];
#pragma unroll
      for (int m = 0; m < M_REP; m++)
        af[m] = *(const bf16x8*)(&As[wr * WM + m * 16 + l15][ks + l4 * 8]);
#pragma unroll
      for (int n = 0; n < N_REP; n++)
        bfr[n] = *(const bf16x8*)(&Bs[wc * WN + n * 16 + l15][ks + l4 * 8]);
#pragma unroll
      for (int m = 0; m < M_REP; m++)
#pragma unroll
        for (int n = 0; n < N_REP; n++)
          acc[m][n] = __builtin_amdgcn_mfma_f32_16x16x32_bf16(af[m], bfr[n], acc[m][n], 0, 0, 0);
    }
    __syncthreads();
  }
  // C write (+ optional bias/BN/ReLU epilogue)
#pragma unroll
  for (int m = 0; m < M_REP; m++) {
#pragma unroll
    for (int r = 0; r < 4; r++) {
      int grow = bm + wr * WM + m * 16 + l4 * 4 + r;
      if (grow >= M) continue;
#pragma unroll
      for (int n = 0; n < N_REP; n++) {
        int gcol = bn + wc * WN + n * 16 + l15;
        if (gcol >= Nc) continue;
        float v = acc[m][n][r];
        if (EPI) {
          v += bias[gcol];
          v = (v - bnrm[gcol]) * (bng[gcol] * rsqrtf(bnrv[gcol] + BN_EPS)) + bnb[gcol];
          v = fmaxf(v, 0.f);
        }
        Cout[(size_t)grow * ldc + gcol] = f2b(v);
      }
    }
  }
  // fused attention dots: wave's WN cols == one head
  if (ATTN_H > 0) {
    int h = blockIdx.y * NWN + wc;
#pragma unroll
    for (int m = 0; m < M_REP; m++) {
#pragma unroll
      for (int r = 0; r < 4; r++) {
        float s1 = 0.f, s2 = 0.f;
#pragma unroll
        for (int n = 0; n < N_REP; n++) {
          float av = acc[m][n][r];
          int cc = n * 16 + l15;
          s1 += av * a_s[h * WN + cc];
          s2 += av * a_d[h * WN + cc];
        }
#pragma unroll
        for (int off = 1; off < 16; off <<= 1) { s1 += __shfl_xor(s1, off); s2 += __shfl_xor(s2, off); }
        int grow = bm + wr * WM + m * 16 + l4 * 4 + r;
        if (l15 == 0 && grow < M) {
          asrc[grow * ATTN_H + h] = s1;
          adst[grow * ATTN_H + h] = s2;
        }
      }
    }
  }
}

// ---------------- edge logits (CSR order via posE) ----------------
template <int H>
__global__ void k_edge_logit(const int* __restrict__ src, const int* __restrict__ dst,
                             const float* __restrict__ eattr, const int* __restrict__ posE,
                             const float* __restrict__ asrc, const float* __restrict__ adst,
                             const float* __restrict__ w_att, float* __restrict__ logitC, int E) {
  int e = blockIdx.x * blockDim.x + threadIdx.x;
  if (e >= E) return;
  float ea[7];
#pragma unroll
  for (int d = 0; d < 7; d++) ea[d] = eattr[e * 7 + d];
  int s = src[e], dn = dst[e];
  int pos = posE[e];
  if (H == 4) {
    f32x4 va = *(const f32x4*)(asrc + s * 4);
    f32x4 vd = *(const f32x4*)(adst + dn * 4);
    f32x4 o;
#pragma unroll
    for (int h = 0; h < 4; h++) {
      float ae = 0.f;
#pragma unroll
      for (int d = 0; d < 7; d++) ae += ea[d] * w_att[d * 4 + h];
      o[h] = leaky(va[h] + vd[h] + ae);
    }
    *(f32x4*)(logitC + (size_t)pos * 4) = o;
  } else {
    float ae = 0.f;
#pragma unroll
    for (int d = 0; d < 7; d++) ae += ea[d] * w_att[d];
    logitC[pos] = leaky(asrc[s] + adst[dn] + ae);
  }
}

// ---------------- L1 gather in x-space ----------------
__global__ __launch_bounds__(256) void k_gather_x(
    const int* __restrict__ rowStart, const int* __restrict__ csrSrc,
    const float* __restrict__ logitC, const float* __restrict__ loopAttr,
    const float* __restrict__ w_att, const float* __restrict__ asrc, const float* __restrict__ adst,
    const u16* __restrict__ xbf, u16* __restrict__ aggOut, int Nn) {
  int wid = threadIdx.x >> 6;
  int n = blockIdx.x * 4 + wid;
  if (n >= Nn) return;
  int lane = threadIdx.x & 63;
  __shared__ float pbuf[4][64 * 4];
  int r0 = rowStart[n], r1 = rowStart[n + 1];

  f32x4 va = *(const f32x4*)(asrc + n * 4);
  f32x4 vd = *(const f32x4*)(adst + n * 4);
  float la[7];
#pragma unroll
  for (int d = 0; d < 7; d++) la[d] = loopAttr[n * 7 + d];
  f32x4 ls;
#pragma unroll
  for (int h = 0; h < 4; h++) {
    float ae = 0.f;
#pragma unroll
    for (int d = 0; d < 7; d++) ae += la[d] * w_att[d * 4 + h];
    ls[h] = leaky(va[h] + vd[h] + ae);
  }

  f32x4 m = ls;
  f32x4 denl = {0.f, 0.f, 0.f, 0.f};
  f32x4 acc = {0.f, 0.f, 0.f, 0.f};

  const f32x4* L4 = (const f32x4*)logitC;
  for (int base = r0; base < r1; base += 64) {
    int slot = base + lane;
    bool valid = slot < r1;
    f32x4 lg = valid ? L4[slot] : (f32x4){-1e30f, -1e30f, -1e30f, -1e30f};
    int srcl = valid ? csrSrc[slot] : 0;
    f32x4 mc = lg;
#pragma unroll
    for (int off = 1; off < 64; off <<= 1) {
#pragma unroll
      for (int h = 0; h < 4; h++) mc[h] = fmaxf(mc[h], __shfl_xor(mc[h], off));
    }
    f32x4 rr;
#pragma unroll
    for (int h = 0; h < 4; h++) {
      float mn = fmaxf(m[h], mc[h]);
      rr[h] = __expf(m[h] - mn);
      m[h] = mn;
      denl[h] *= rr[h];
      acc[h] *= rr[h];
    }
    f32x4 ex;
#pragma unroll
    for (int h = 0; h < 4; h++) ex[h] = valid ? __expf(lg[h] - m[h]) : 0.f;
#pragma unroll
    for (int h = 0; h < 4; h++) denl[h] += ex[h];
    *(f32x4*)(&pbuf[wid][lane * 4]) = ex;
    int nv = r1 - base; if (nv > 64) nv = 64;
    int j = 0;
    for (; j + 1 < nv; j += 2) {
      int s0 = __shfl(srcl, j);
      int s1 = __shfl(srcl, j + 1);
      f32x4 p0 = *(const f32x4*)(&pbuf[wid][j * 4]);
      f32x4 p1 = *(const f32x4*)(&pbuf[wid][(j + 1) * 4]);
      float x0 = b2f(xbf[(size_t)s0 * 64 + lane]);
      float x1 = b2f(xbf[(size_t)s1 * 64 + lane]);
#pragma unroll
      for (int h = 0; h < 4; h++) acc[h] += p0[h] * x0 + p1[h] * x1;
    }
    if (j < nv) {
      int s0 = __shfl(srcl, j);
      f32x4 p0 = *(const f32x4*)(&pbuf[wid][j * 4]);
      float x0 = b2f(xbf[(size_t)s0 * 64 + lane]);
#pragma unroll
      for (int h = 0; h < 4; h++) acc[h] += p0[h] * x0;
    }
  }
  f32x4 exs;
#pragma unroll
  for (int h = 0; h < 4; h++) exs[h] = __expf(ls[h] - m[h]);
  f32x4 den;
#pragma unroll
  for (int h = 0; h < 4; h++) {
    float v = denl[h];
#pragma unroll
    for (int off = 1; off < 64; off <<= 1) v += __shfl_xor(v, off);
    den[h] = v + exs[h];
  }
  {
    float xn = b2f(xbf[(size_t)n * 64 + lane]);
#pragma unroll
    for (int h = 0; h < 4; h++) acc[h] += exs[h] * xn;
  }
#pragma unroll
  for (int h = 0; h < 4; h++) pbuf[wid][h * 64 + lane] = acc[h] / den[h];
  u16x4 ov;
#pragma unroll
  for (int jj = 0; jj < 4; jj++) ov[jj] = f2b(pbuf[wid][lane * 4 + jj]);
  *(u16x4*)(aggOut + (size_t)n * 256 + lane * 4) = ov;
}

// ---------------- gather (H=4) post-GEMM ----------------
template <int C, int CPL>
__global__ __launch_bounds__(256) void k_gather4(
    const int* __restrict__ rowStart, const int* __restrict__ csrSrc,
    const float* __restrict__ logitC, const float* __restrict__ loopAttr,
    const float* __restrict__ w_att, const float* __restrict__ asrc, const float* __restrict__ adst,
    const u16* __restrict__ hbuf, const float* __restrict__ bias,
    const float* __restrict__ bng, const float* __restrict__ bnb,
    const float* __restrict__ bnrm, const float* __restrict__ bnrv,
    u16* __restrict__ outbuf, int Nn) {
  constexpr int HC = 4 * C;
  typedef __attribute__((ext_vector_type(CPL))) unsigned short u16v;
  int wid = threadIdx.x >> 6;
  int n = blockIdx.x * 4 + wid;
  if (n >= Nn) return;
  int lane = threadIdx.x & 63;
  int hs = lane >> 4;
  __shared__ float pbuf[4][64 * 4];
  int r0 = rowStart[n], r1 = rowStart[n + 1];

  f32x4 va = *(const f32x4*)(asrc + n * 4);
  f32x4 vd = *(const f32x4*)(adst + n * 4);
  float la[7];
#pragma unroll
  for (int d = 0; d < 7; d++) la[d] = loopAttr[n * 7 + d];
  f32x4 ls;
#pragma unroll
  for (int h = 0; h < 4; h++) {
    float ae = 0.f;
#pragma unroll
    for (int d = 0; d < 7; d++) ae += la[d] * w_att[d * 4 + h];
    ls[h] = leaky(va[h] + vd[h] + ae);
  }

  f32x4 m = ls;
  f32x4 denl = {0.f, 0.f, 0.f, 0.f};
  float acc[CPL];
#pragma unroll
  for (int jj = 0; jj < CPL; jj++) acc[jj] = 0.f;

  const f32x4* L4 = (const f32x4*)logitC;
  for (int base = r0; base < r1; base += 64) {
    int slot = base + lane;
    bool valid = slot < r1;
    f32x4 lg = valid ? L4[slot] : (f32x4){-1e30f, -1e30f, -1e30f, -1e30f};
    int srcl = valid ? csrSrc[slot] : 0;
    f32x4 mc = lg;
#pragma unroll
    for (int off = 1; off < 64; off <<= 1) {
#pragma unroll
      for (int h = 0; h < 4; h++) mc[h] = fmaxf(mc[h], __shfl_xor(mc[h], off));
    }
    f32x4 rr;
#pragma unroll
    for (int h = 0; h < 4; h++) {
      float mn = fmaxf(m[h], mc[h]);
      rr[h] = __expf(m[h] - mn);
      m[h] = mn;
      denl[h] *= rr[h];
    }
    float rrh = sel4(rr, hs);
#pragma unroll
    for (int jj = 0; jj < CPL; jj++) acc[jj] *= rrh;
    f32x4 ex;
#pragma unroll
    for (int h = 0; h < 4; h++) ex[h] = valid ? __expf(lg[h] - m[h]) : 0.f;
#pragma unroll
    for (int h = 0; h < 4; h++) denl[h] += ex[h];
    *(f32x4*)(&pbuf[wid][lane * 4]) = ex;
    int nv = r1 - base; if (nv > 64) nv = 64;
    int j = 0;
    for (; j + 1 < nv; j += 2) {
      int s0 = __shfl(srcl, j);
      int s1 = __shfl(srcl, j + 1);
      float p0 = pbuf[wid][j * 4 + hs];
      float p1 = pbuf[wid][(j + 1) * 4 + hs];
      u16v h0 = *(const u16v*)(hbuf + (size_t)s0 * HC + lane * CPL);
      u16v h1 = *(const u16v*)(hbuf + (size_t)s1 * HC + lane * CPL);
#pragma unroll
      for (int jj = 0; jj < CPL; jj++) acc[jj] += p0 * b2f(h0[jj]) + p1 * b2f(h1[jj]);
    }
    if (j < nv) {
      int s0 = __shfl(srcl, j);
      float p0 = pbuf[wid][j * 4 + hs];
      u16v h0 = *(const u16v*)(hbuf + (size_t)s0 * HC + lane * CPL);
#pragma unroll
      for (int jj = 0; jj < CPL; jj++) acc[jj] += p0 * b2f(h0[jj]);
    }
  }
  f32x4 exs;
#pragma unroll
  for (int h = 0; h < 4; h++) exs[h] = __expf(ls[h] - m[h]);
  f32x4 den;
#pragma unroll
  for (int h = 0; h < 4; h++) {
    float v = denl[h];
#pragma unroll
    for (int off = 1; off < 64; off <<= 1) v += __shfl_xor(v, off);
    den[h] = v + exs[h];
  }
  {
    float ps = sel4(exs, hs);
    u16v hN = *(const u16v*)(hbuf + (size_t)n * HC + lane * CPL);
#pragma unroll
    for (int jj = 0; jj < CPL; jj++) acc[jj] += ps * b2f(hN[jj]);
  }
  float dh = sel4(den, hs);
  u16v ov;
#pragma unroll
  for (int jj = 0; jj < CPL; jj++) {
    int c = lane * CPL + jj;
    float v = acc[jj] / dh + bias[c];
    v = (v - bnrm[c]) * (bng[c] * rsqrtf(bnrv[c] + BN_EPS)) + bnb[c];
    ov[jj] = f2b(fmaxf(v, 0.f));
  }
  *(u16v*)(outbuf + (size_t)n * HC + lane * CPL) = ov;
}

// ---------------- gather (H=1, C=32) ----------------
__global__ __launch_bounds__(256) void k_gather_L3(
    const int* __restrict__ rowStart, const int* __restrict__ csrSrc,
    const float* __restrict__ logitC, const float* __restrict__ loopAttr,
    const float* __restrict__ w_att, const float* __restrict__ asrc, const float* __restrict__ adst,
    const u16* __restrict__ hbuf, const float* __restrict__ bias,
    const float* __restrict__ bng, const float* __restrict__ bnb,
    const float* __restrict__ bnrm, const float* __restrict__ bnrv,
    u16* __restrict__ outbuf, int Nn) {
  int n = blockIdx.x * 4 + (threadIdx.x >> 6);
  if (n >= Nn) return;
  int lane = threadIdx.x & 63;
  int cl = lane & 31, half = lane >> 5;
  int r0 = rowStart[n], r1 = rowStart[n + 1];
  float ae = 0.f;
#pragma unroll
  for (int d = 0; d < 7; d++) ae += loopAttr[n * 7 + d] * w_att[d];
  float ls = leaky(asrc[n] + adst[n] + ae);

  float m = ls;
  for (int j = r0 + lane; j < r1; j += 64) m = fmaxf(m, logitC[j]);
  for (int off = 32; off > 0; off >>= 1) m = fmaxf(m, __shfl_xor(m, off));
  float den = 0.f;
  for (int j = r0 + lane; j < r1; j += 64) den += __expf(logitC[j] - m);
  for (int off = 32; off > 0; off >>= 1) den += __shfl_xor(den, off);
  den += __expf(ls - m);

  float acc = 0.f;
  for (int j = r0 + half; j < r1; j += 2) {
    float p = __expf(logitC[j] - m);
    int s = csrSrc[j];
    acc += p * b2f(hbuf[(size_t)s * 32 + cl]);
  }
  if (half == 0) acc += __expf(ls - m) * b2f(hbuf[(size_t)n * 32 + cl]);
  acc += __shfl_xor(acc, 32);
  if (half == 0) {
    float v = acc / den + bias[cl];
    v = (v - bnrm[cl]) * (bng[cl] * rsqrtf(bnrv[cl] + BN_EPS)) + bnb[cl];
    outbuf[(size_t)n * 32 + cl] = f2b(fmaxf(v, 0.f));
  }
}

// ---------------- fused pooling + MLP ----------------
__global__ __launch_bounds__(256) void k_pool_mlp(
    const u16* __restrict__ h3, const int* __restrict__ batch, int Nn,
    const float* __restrict__ lw1, const float* __restrict__ lb1,
    const float* __restrict__ lw2, const float* __restrict__ lb2,
    float* __restrict__ out) {
  int g = blockIdx.x;
  int tid = threadIdx.x;
  __shared__ int s_lo, s_hi;
  if (tid == 0) {
    int lo = 0, hi = Nn;
    while (lo < hi) { int mid = (lo + hi) >> 1; if (batch[mid] < g) lo = mid + 1; else hi = mid; }
    s_lo = lo;
    int lo2 = lo, hi2 = Nn;
    while (lo2 < hi2) { int mid = (lo2 + hi2) >> 1; if (batch[mid] < g + 1) lo2 = mid + 1; else hi2 = mid; }
    s_hi = lo2;
  }
  __syncthreads();
  int lo = s_lo, hi = s_hi;
  int c = tid & 31, r = tid >> 5;
  float sum = 0.f, mx = -1e30f;
  for (int n = lo + r; n < hi; n += 8) {
    float v = b2f(h3[(size_t)n * 32 + c]);
    sum += v;
    mx = fmaxf(mx, v);
  }
  __shared__ float ssum[8][32];
  __shared__ float smax[8][32];
  ssum[r][c] = sum;
  smax[r][c] = mx;
  __syncthreads();
  __shared__ float z[64];
  __shared__ float zz1[32];
  if (tid < 32) {
    float s = 0.f, m2 = -1e30f;
#pragma unroll
    for (int rr = 0; rr < 8; rr++) { s += ssum[rr][tid]; m2 = fmaxf(m2, smax[rr][tid]); }
    int cnt = hi - lo;
    z[tid] = s / fmaxf((float)cnt, 1.0f);
    z[32 + tid] = (cnt > 0) ? m2 : 0.f;
  }
  __syncthreads();
  if (tid < 32) {
    float s = lb1[tid];
    for (int k = 0; k < 64; k++) s += z[k] * lw1[k * 32 + tid];
    zz1[tid] = fmaxf(s, 0.f);
  }
  __syncthreads();
  if (tid == 0) {
    float s = lb2[0];
    for (int j = 0; j < 32; j++) s += zz1[j] * lw2[j];
    out[g] = 1.f / (1.f + expf(-s));
  }
}

// ---------------- driver ----------------
extern "C" void kernel_launch(void* const* d_in, const int* in_sizes, int n_in,
                              void* d_out, int out_size, void* d_ws, size_t ws_size,
                              hipStream_t stream) {
  const float* x     = (const float*)d_in[0];
  const int*   eidx  = (const int*)d_in[1];
  const float* eattr = (const float*)d_in[2];
  const int*   batch = (const int*)d_in[3];
  int N = in_sizes[0] / 64;
  int E = in_sizes[1] / 2;
  int NG = out_size;
  const int* src = eidx;
  const int* dst = eidx + E;

  const float* W[3]  = {(const float*)d_in[4],  (const float*)d_in[14], (const float*)d_in[24]};
  const float* AS[3] = {(const float*)d_in[5],  (const float*)d_in[15], (const float*)d_in[25]};
  const float* AD[3] = {(const float*)d_in[6],  (const float*)d_in[16], (const float*)d_in[26]};
  const float* WE[3] = {(const float*)d_in[7],  (const float*)d_in[17], (const float*)d_in[27]};
  const float* AE[3] = {(const float*)d_in[8],  (const float*)d_in[18], (const float*)d_in[28]};
  const float* B[3]  = {(const float*)d_in[9],  (const float*)d_in[19], (const float*)d_in[29]};
  const float* G[3]  = {(const float*)d_in[10], (const float*)d_in[20], (const float*)d_in[30]};
  const float* BT[3] = {(const float*)d_in[11], (const float*)d_in[21], (const float*)d_in[31]};
  const float* RM[3] = {(const float*)d_in[12], (const float*)d_in[22], (const float*)d_in[32]};
  const float* RV[3] = {(const float*)d_in[13], (const float*)d_in[23], (const float*)d_in[33]};
  const float* lw1 = (const float*)d_in[34];
  const float* lb1 = (const float*)d_in[35];
  const float* lw2 = (const float*)d_in[36];
  const float* lb2 = (const float*)d_in[37];

  char* wp = (char*)d_ws;
  auto alloc = [&](size_t bytes) -> void* {
    void* p = (void*)wp;
    wp += (bytes + 255) & ~(size_t)255;
    return p;
  };
  u16*   xbf      = (u16*)alloc((size_t)N * 64 * 2);
  u16*   aggB     = (u16*)alloc((size_t)N * 256 * 2);
  u16*   bufH     = (u16*)alloc((size_t)N * 512 * 2);
  u16*   bufA     = (u16*)alloc((size_t)N * 512 * 2);
  u16*   Wt1      = (u16*)alloc((size_t)512 * 64 * 2);
  u16*   Wt2      = (u16*)alloc((size_t)256 * 512 * 2);
  u16*   Wt3      = (u16*)alloc((size_t)32 * 256 * 2);
  int*   degInt   = (int*)alloc((size_t)N * 4);
  int*   cursor   = (int*)alloc((size_t)N * 4);
  int*   rowStart = (int*)alloc((size_t)(N + 1) * 4);
  float* loopAttr = (float*)alloc((size_t)N * 7 * 4);
  int*   csrSrc   = (int*)alloc((size_t)E * 4);
  int*   csrEid   = (int*)alloc((size_t)E * 4);
  int*   posE     = (int*)alloc((size_t)E * 4);
  float* logitC   = (float*)alloc((size_t)E * 4 * 4);
  float* asrc     = (float*)alloc((size_t)N * 4 * 4);
  float* adst     = (float*)alloc((size_t)N * 4 * 4);
  float* watt1    = (float*)alloc(28 * 4);
  float* watt2    = (float*)alloc(28 * 4);
  float* watt3    = (float*)alloc(7 * 4);
  float* ws1      = (float*)alloc(64 * 4 * 4);
  float* wd1      = (float*)alloc(64 * 4 * 4);

  // ---- fused prep (weights + zero degInt/cursor)
  int prepTotal = 172352 + 2 * N;
  k_prep<<<(prepTotal + 255) / 256, 256, 0, stream>>>(
      W[0], W[1], W[2], AS[0], AD[0], WE[0], AE[0], WE[1], AE[1], WE[2], AE[2],
      Wt1, Wt2, Wt3, ws1, wd1, watt1, watt2, watt3, degInt, cursor, N);

  // ---- CSR build
  k_deg<<<(E + 255) / 256, 256, 0, stream>>>(dst, degInt, E);
  k_scan<<<1, 1024, 0, stream>>>(degInt, rowStart, N);
  k_fill_csr<<<(E + 255) / 256, 256, 0, stream>>>(src, dst, rowStart, cursor, csrSrc, csrEid, posE, E);
  k_loop_gather<<<(N * 7 + 255) / 256, 256, 0, stream>>>(rowStart, csrEid, eattr, loopAttr, N);

  int gmM = (N + 127) / 128;
  int nb4 = (N + 3) / 4;

  // ---- layer 1: x-space aggregation, then 4 head-GEMMs with fused epilogue
  k_cast_attn_x<<<nb4, 256, 0, stream>>>(x, xbf, ws1, wd1, asrc, adst, N);
  k_edge_logit<4><<<(E + 255) / 256, 256, 0, stream>>>(src, dst, eattr, posE, asrc, adst, watt1, logitC, E);
  k_gather_x<<<nb4, 256, 0, stream>>>(rowStart, csrSrc, logitC, loopAttr, watt1, asrc, adst, xbf, aggB, N);
  k_gemm_mfma<128, 128, 64, 64, true, 0><<<dim3(gmM, 1, 4), 256, 0, stream>>>(
      aggB, Wt1, bufA, N, 64, 128, 256, 512, 64, 128 * 64, 128,
      B[0], G[0], BT[0], RM[0], RV[0], nullptr, nullptr, nullptr, nullptr);

  // ---- layer 2: GEMM with fused attn dots (WN=64=C), then gather
  k_gemm_mfma<128, 128, 64, 64, false, 4><<<dim3(gmM, 2, 1), 256, 0, stream>>>(
      bufA, Wt2, bufH, N, 512, 256, 512, 256, 0, 0, 0,
      nullptr, nullptr, nullptr, nullptr, nullptr, AS[1], AD[1], asrc, adst);
  k_edge_logit<4><<<(E + 255) / 256, 256, 0, stream>>>(src, dst, eattr, posE, asrc, adst, watt2, logitC, E);
  k_gather4<64, 4><<<nb4, 256, 0, stream>>>(rowStart, csrSrc, logitC, loopAttr, watt2, asrc, adst,
                                            bufH, B[1], G[1], BT[1], RM[1], RV[1], bufA, N);

  // ---- layer 3: GEMM with fused attn dots (WN=32=C, H=1), then gather
  k_gemm_mfma<128, 32, 32, 32, false, 1><<<dim3(gmM, 1, 1), 256, 0, stream>>>(
      bufA, Wt3, bufH, N, 256, 32, 256, 32, 0, 0, 0,
      nullptr, nullptr, nullptr, nullptr, nullptr, AS[2], AD[2], asrc, adst);
  k_edge_logit<1><<<(E + 255) / 256, 256, 0, stream>>>(src, dst, eattr, posE, asrc, adst, watt3, logitC, E);
  k_gather_L3<<<nb4, 256, 0, stream>>>(rowStart, csrSrc, logitC, loopAttr, watt3, asrc, adst,
                                       bufH, B[2], G[2], BT[2], RM[2], RV[2], bufA, N);

  // ---- fused pooling + MLP
  k_pool_mlp<<<NG, 256, 0, stream>>>(bufA, batch, N, lw1, lb1, lw2, lb2, (float*)d_out);
}

// Round 8
// 265.306 us; speedup vs baseline: 1.2817x; 1.0777x over previous
//
#include <hip/hip_runtime.h>
#include <math.h>

#define NEG_SLOPE 0.2f
#define BN_EPS 1e-5f

typedef __attribute__((ext_vector_type(8))) short bf16x8;
typedef __attribute__((ext_vector_type(4))) float f32x4;
typedef unsigned short u16;
typedef __attribute__((ext_vector_type(4))) unsigned short u16x4;

static __device__ __forceinline__ float leaky(float v) { return v > 0.f ? v : NEG_SLOPE * v; }
static __device__ __forceinline__ float b2f(u16 b) { return __uint_as_float(((unsigned)b) << 16); }
static __device__ __forceinline__ u16 f2b(float f) {
  unsigned u = __float_as_uint(f);
  u += 0x7FFF + ((u >> 16) & 1);
  return (u16)(u >> 16);
}
static __device__ __forceinline__ float sel4(f32x4 v, int hs) {
  float a = (hs & 1) ? v[1] : v[0];
  float b = (hs & 1) ? v[3] : v[2];
  return (hs & 2) ? b : a;
}

// ---------------- fused prep: weight transposes + attn-weight projections + zero deg/cursor ----------------
__global__ void k_prep(const float* __restrict__ W1, const float* __restrict__ W2, const float* __restrict__ W3,
                       const float* __restrict__ AS1, const float* __restrict__ AD1,
                       const float* __restrict__ WE1, const float* __restrict__ AE1,
                       const float* __restrict__ WE2, const float* __restrict__ AE2,
                       const float* __restrict__ WE3, const float* __restrict__ AE3,
                       u16* __restrict__ Wt1, u16* __restrict__ Wt2, u16* __restrict__ Wt3,
                       float* __restrict__ ws1, float* __restrict__ wd1,
                       float* __restrict__ watt1, float* __restrict__ watt2, float* __restrict__ watt3,
                       int* __restrict__ degInt, int* __restrict__ cursor, int Nn) {
  int idx = blockIdx.x * blockDim.x + threadIdx.x;
  if (idx < 32768) {                       // Wt1 [512][64] <- W1 [64][512]
    int k = idx >> 9, n = idx & 511;
    Wt1[n * 64 + k] = f2b(W1[idx]);
  } else if (idx < 163840) {               // Wt2 [256][512] <- W2 [512][256]
    int i = idx - 32768;
    int k = i >> 8, n = i & 255;
    Wt2[n * 512 + k] = f2b(W2[i]);
  } else if (idx < 172032) {               // Wt3 [32][256] <- W3 [256][32]
    int i = idx - 163840;
    int k = i >> 5, n = i & 31;
    Wt3[n * 256 + k] = f2b(W3[i]);
  } else if (idx < 172288) {               // ws1/wd1 [64][4]
    int t = idx - 172032;
    int k = t >> 2, h = t & 3;
    float s1 = 0.f, s2 = 0.f;
    for (int c = 0; c < 128; c++) {
      float w = W1[k * 512 + h * 128 + c];
      s1 += w * AS1[h * 128 + c];
      s2 += w * AD1[h * 128 + c];
    }
    ws1[t] = s1; wd1[t] = s2;
  } else if (idx < 172316) {               // watt1 [7][4]
    int t = idx - 172288;
    int d = t >> 2, h = t & 3;
    float s = 0.f;
    for (int c = 0; c < 128; c++) s += WE1[d * 512 + h * 128 + c] * AE1[h * 128 + c];
    watt1[t] = s;
  } else if (idx < 172344) {               // watt2 [7][4]
    int t = idx - 172316;
    int d = t >> 2, h = t & 3;
    float s = 0.f;
    for (int c = 0; c < 64; c++) s += WE2[d * 256 + h * 64 + c] * AE2[h * 64 + c];
    watt2[t] = s;
  } else if (idx < 172351) {               // watt3 [7]
    int d = idx - 172344;
    float s = 0.f;
    for (int c = 0; c < 32; c++) s += WE3[d * 32 + c] * AE3[c];
    watt3[d] = s;
  } else if (idx >= 172352 && idx < 172352 + Nn) {
    degInt[idx - 172352] = 0;
  } else if (idx >= 172352 + Nn && idx < 172352 + 2 * Nn) {
    cursor[idx - 172352 - Nn] = 0;
  }
}

// ---------------- CSR build ----------------
__global__ void k_deg(const int* __restrict__ dst, int* __restrict__ degInt, int E) {
  int e = blockIdx.x * blockDim.x + threadIdx.x;
  if (e < E) atomicAdd(&degInt[dst[e]], 1);
}

__global__ void k_scan(const int* __restrict__ degInt, int* __restrict__ rowStart, int n) {
  __shared__ int sums[1024];
  int tid = threadIdx.x;
  int per = (n + 1023) / 1024;
  int start = tid * per;
  int end = start + per; if (end > n) end = n;
  int s = 0;
  for (int i = start; i < end; i++) s += degInt[i];
  sums[tid] = s;
  __syncthreads();
  for (int off = 1; off < 1024; off <<= 1) {
    int v = (tid >= off) ? sums[tid - off] : 0;
    __syncthreads();
    sums[tid] += v;
    __syncthreads();
  }
  int base = (tid > 0) ? sums[tid - 1] : 0;
  for (int i = start; i < end; i++) { rowStart[i] = base; base += degInt[i]; }
  if (tid == 1023) rowStart[n] = sums[1023];
}

__global__ void k_fill_csr(const int* __restrict__ src, const int* __restrict__ dst,
                           const int* __restrict__ rowStart, int* __restrict__ cursor,
                           int* __restrict__ csrSrc, int* __restrict__ posE, int E) {
  int e = blockIdx.x * blockDim.x + threadIdx.x;
  if (e >= E) return;
  int d = dst[e];
  int pos = rowStart[d] + atomicAdd(&cursor[d], 1);
  csrSrc[pos] = src[e];
  posE[e] = pos;
}

// ---------------- one pass over eattr: all 9 head ae-slots, scattered to CSR order ----------------
__global__ void k_ae(const float* __restrict__ eattr, const int* __restrict__ posE,
                     const float* __restrict__ watt1, const float* __restrict__ watt2,
                     const float* __restrict__ watt3,
                     float* __restrict__ ae1, float* __restrict__ ae2, float* __restrict__ ae3, int E) {
  int e = blockIdx.x * blockDim.x + threadIdx.x;
  if (e >= E) return;
  float ea[7];
#pragma unroll
  for (int d = 0; d < 7; d++) ea[d] = eattr[e * 7 + d];
  int pos = posE[e];
  f32x4 o1, o2;
#pragma unroll
  for (int h = 0; h < 4; h++) {
    float a1 = 0.f, a2 = 0.f;
#pragma unroll
    for (int d = 0; d < 7; d++) { a1 += ea[d] * watt1[d * 4 + h]; a2 += ea[d] * watt2[d * 4 + h]; }
    o1[h] = a1; o2[h] = a2;
  }
  float a3 = 0.f;
#pragma unroll
  for (int d = 0; d < 7; d++) a3 += ea[d] * watt3[d];
  *(f32x4*)(ae1 + (size_t)pos * 4) = o1;
  *(f32x4*)(ae2 + (size_t)pos * 4) = o2;
  ae3[pos] = a3;
}

// ---------------- fused x cast + L1 attention dots ----------------
__global__ __launch_bounds__(256) void k_cast_attn_x(const float* __restrict__ x, u16* __restrict__ xbf,
                                                     const float* __restrict__ ws, const float* __restrict__ wd,
                                                     float* __restrict__ asrc, float* __restrict__ adst, int Nn) {
  int n = blockIdx.x * 4 + (threadIdx.x >> 6);
  if (n >= Nn) return;
  int lane = threadIdx.x & 63;
  float xv = x[(size_t)n * 64 + lane];
  xbf[(size_t)n * 64 + lane] = f2b(xv);
  f32x4 vs = *(const f32x4*)(ws + lane * 4);
  f32x4 vd = *(const f32x4*)(wd + lane * 4);
  f32x4 s1, s2;
#pragma unroll
  for (int h = 0; h < 4; h++) { s1[h] = xv * vs[h]; s2[h] = xv * vd[h]; }
#pragma unroll
  for (int off = 1; off < 64; off <<= 1) {
#pragma unroll
    for (int h = 0; h < 4; h++) { s1[h] += __shfl_xor(s1[h], off); s2[h] += __shfl_xor(s2[h], off); }
  }
  if (lane == 0) {
    *(f32x4*)(asrc + n * 4) = s1;
    *(f32x4*)(adst + n * 4) = s2;
  }
}

// ---------------- MFMA bf16 GEMM with optional epilogue / fused attn dots ----------------
template <int BM, int BN, int WM, int WN, bool EPI, int ATTN_H>
__global__ __launch_bounds__(256) void k_gemm_mfma(const u16* __restrict__ A,
                                                   const u16* __restrict__ Bt,
                                                   u16* __restrict__ Cout,
                                                   int M, int K, int Nc, int lda, int ldc,
                                                   int AzOff, int BzOff, int CzOff,
                                                   const float* __restrict__ bias,
                                                   const float* __restrict__ bng,
                                                   const float* __restrict__ bnb,
                                                   const float* __restrict__ bnrm,
                                                   const float* __restrict__ bnrv,
                                                   const float* __restrict__ a_s,
                                                   const float* __restrict__ a_d,
                                                   float* __restrict__ asrc,
                                                   float* __restrict__ adst) {
  constexpr int BK = 64;
  constexpr int LDT = BK + 8;
  __shared__ u16 As[BM][LDT];
  __shared__ u16 Bs[BN][LDT];
  constexpr int NWN = BN / WN;
  constexpr int M_REP = WM / 16;
  constexpr int N_REP = WN / 16;
  int z = blockIdx.z;
  A += (size_t)z * AzOff;
  Bt += (size_t)z * BzOff;
  Cout += (size_t)z * CzOff;
  if (EPI) {
    bias += (size_t)z * CzOff; bng += (size_t)z * CzOff; bnb += (size_t)z * CzOff;
    bnrm += (size_t)z * CzOff; bnrv += (size_t)z * CzOff;
  }
  int tid = threadIdx.x;
  int wid = tid >> 6, lane = tid & 63;
  int wr = wid / NWN, wc = wid % NWN;
  int bm = blockIdx.x * BM, bn = blockIdx.y * BN;
  int l15 = lane & 15, l4 = lane >> 4;

  f32x4 acc[M_REP][N_REP];
#pragma unroll
  for (int m = 0; m < M_REP; m++)
#pragma unroll
    for (int n = 0; n < N_REP; n++) acc[m][n] = (f32x4){0.f, 0.f, 0.f, 0.f};

  for (int k0 = 0; k0 < K; k0 += BK) {
    constexpr int CHA = BM * BK / 8;
#pragma unroll
    for (int ch0 = 0; ch0 < CHA; ch0 += 256) {
      int ch = ch0 + tid;
      int row = ch >> 3, cc = (ch & 7) * 8;
      int gr = bm + row;
      bf16x8 v = {};
      if (gr < M) v = *(const bf16x8*)(A + (size_t)gr * lda + k0 + cc);
      *(bf16x8*)(&As[row][cc]) = v;
    }
    constexpr int CHB = BN * BK / 8;
#pragma unroll
    for (int ch0 = 0; ch0 < CHB; ch0 += 256) {
      int ch = ch0 + tid;
      int row = ch >> 3, cc = (ch & 7) * 8;
      int gr = bn + row;
      bf16x8 v = {};
      if (gr < Nc) v = *(const bf16x8*)(Bt + (size_t)gr * K + k0 + cc);
      *(bf16x8*)(&Bs[row][cc]) = v;
    }
    __syncthreads();
#pragma unroll
    for (int ks = 0; ks < BK; ks += 32) {
      bf16x8 af[M_REP], bfr[N_REP];
#pragma unroll
      for (int m = 0; m < M_REP; m++)
        af[m] = *(const bf16x8*)(&As[wr * WM + m * 16 + l15][ks + l4 * 8]);
#pragma unroll
      for (int n = 0; n < N_REP; n++)
        bfr[n] = *(const bf16x8*)(&Bs[wc * WN + n * 16 + l15][ks + l4 * 8]);
#pragma unroll
      for (int m = 0; m < M_REP; m++)
#pragma unroll
        for (int n = 0; n < N_REP; n++)
          acc[m][n] = __builtin_amdgcn_mfma_f32_16x16x32_bf16(af[m], bfr[n], acc[m][n], 0, 0, 0);
    }
    __syncthreads();
  }
#pragma unroll
  for (int m = 0; m < M_REP; m++) {
#pragma unroll
    for (int r = 0; r < 4; r++) {
      int grow = bm + wr * WM + m * 16 + l4 * 4 + r;
      if (grow >= M) continue;
#pragma unroll
      for (int n = 0; n < N_REP; n++) {
        int gcol = bn + wc * WN + n * 16 + l15;
        if (gcol >= Nc) continue;
        float v = acc[m][n][r];
        if (EPI) {
          v += bias[gcol];
          v = (v - bnrm[gcol]) * (bng[gcol] * rsqrtf(bnrv[gcol] + BN_EPS)) + bnb[gcol];
          v = fmaxf(v, 0.f);
        }
        Cout[(size_t)grow * ldc + gcol] = f2b(v);
      }
    }
  }
  if (ATTN_H > 0) {
    int h = blockIdx.y * NWN + wc;
#pragma unroll
    for (int m = 0; m < M_REP; m++) {
#pragma unroll
      for (int r = 0; r < 4; r++) {
        float s1 = 0.f, s2 = 0.f;
#pragma unroll
        for (int n = 0; n < N_REP; n++) {
          float av = acc[m][n][r];
          int cc = n * 16 + l15;
          s1 += av * a_s[h * WN + cc];
          s2 += av * a_d[h * WN + cc];
        }
#pragma unroll
        for (int off = 1; off < 16; off <<= 1) { s1 += __shfl_xor(s1, off); s2 += __shfl_xor(s2, off); }
        int grow = bm + wr * WM + m * 16 + l4 * 4 + r;
        if (l15 == 0 && grow < M) {
          asrc[grow * ATTN_H + h] = s1;
          adst[grow * ATTN_H + h] = s2;
        }
      }
    }
  }
}

// ---------------- L1 gather in x-space (inline logits, inline self via mean-ae) ----------------
__global__ __launch_bounds__(256) void k_gather_x(
    const int* __restrict__ rowStart, const int* __restrict__ csrSrc,
    const float* __restrict__ aeC, const float* __restrict__ asrc, const float* __restrict__ adst,
    const u16* __restrict__ xbf, u16* __restrict__ aggOut, int Nn) {
  int wid = threadIdx.x >> 6;
  int n = blockIdx.x * 4 + wid;
  if (n >= Nn) return;
  int lane = threadIdx.x & 63;
  __shared__ float pbuf[4][64 * 4];
  int r0 = rowStart[n], r1 = rowStart[n + 1];
  f32x4 vaN = *(const f32x4*)(asrc + n * 4);
  f32x4 vdN = *(const f32x4*)(adst + n * 4);

  f32x4 m = {-1e30f, -1e30f, -1e30f, -1e30f};
  f32x4 denl = {0.f, 0.f, 0.f, 0.f};
  f32x4 aes = {0.f, 0.f, 0.f, 0.f};
  f32x4 acc = {0.f, 0.f, 0.f, 0.f};

  const f32x4* AE4 = (const f32x4*)aeC;
  for (int base = r0; base < r1; base += 64) {
    int slot = base + lane;
    bool valid = slot < r1;
    int srcl = 0;
    f32x4 lg = {-1e30f, -1e30f, -1e30f, -1e30f};
    if (valid) {
      srcl = csrSrc[slot];
      f32x4 vaS = *(const f32x4*)(asrc + srcl * 4);
      f32x4 ae = AE4[slot];
#pragma unroll
      for (int h = 0; h < 4; h++) { aes[h] += ae[h]; lg[h] = leaky(vaS[h] + vdN[h] + ae[h]); }
    }
    f32x4 mc = lg;
#pragma unroll
    for (int off = 1; off < 64; off <<= 1) {
#pragma unroll
      for (int h = 0; h < 4; h++) mc[h] = fmaxf(mc[h], __shfl_xor(mc[h], off));
    }
    f32x4 rr;
#pragma unroll
    for (int h = 0; h < 4; h++) {
      float mn = fmaxf(m[h], mc[h]);
      rr[h] = __expf(m[h] - mn);
      m[h] = mn;
      denl[h] *= rr[h];
      acc[h] *= rr[h];
    }
    f32x4 ex;
#pragma unroll
    for (int h = 0; h < 4; h++) ex[h] = valid ? __expf(lg[h] - m[h]) : 0.f;
#pragma unroll
    for (int h = 0; h < 4; h++) denl[h] += ex[h];
    *(f32x4*)(&pbuf[wid][lane * 4]) = ex;
    int nv = r1 - base; if (nv > 64) nv = 64;
    int j = 0;
    for (; j + 1 < nv; j += 2) {
      int s0 = __shfl(srcl, j);
      int s1 = __shfl(srcl, j + 1);
      f32x4 p0 = *(const f32x4*)(&pbuf[wid][j * 4]);
      f32x4 p1 = *(const f32x4*)(&pbuf[wid][(j + 1) * 4]);
      float x0 = b2f(xbf[(size_t)s0 * 64 + lane]);
      float x1 = b2f(xbf[(size_t)s1 * 64 + lane]);
#pragma unroll
      for (int h = 0; h < 4; h++) acc[h] += p0[h] * x0 + p1[h] * x1;
    }
    if (j < nv) {
      int s0 = __shfl(srcl, j);
      f32x4 p0 = *(const f32x4*)(&pbuf[wid][j * 4]);
      float x0 = b2f(xbf[(size_t)s0 * 64 + lane]);
#pragma unroll
      for (int h = 0; h < 4; h++) acc[h] += p0[h] * x0;
    }
  }
  // self-loop via mean-ae, merged after the online loop
  float degf = fmaxf((float)(r1 - r0), 1.0f);
  f32x4 ls, exs;
#pragma unroll
  for (int h = 0; h < 4; h++) {
    float a = aes[h];
#pragma unroll
    for (int off = 1; off < 64; off <<= 1) a += __shfl_xor(a, off);
    ls[h] = leaky(vaN[h] + vdN[h] + a / degf);
    float mn = fmaxf(m[h], ls[h]);
    float sc = __expf(m[h] - mn);
    m[h] = mn;
    denl[h] *= sc;
    acc[h] *= sc;
    exs[h] = __expf(ls[h] - mn);
  }
  f32x4 den;
#pragma unroll
  for (int h = 0; h < 4; h++) {
    float v = denl[h];
#pragma unroll
    for (int off = 1; off < 64; off <<= 1) v += __shfl_xor(v, off);
    den[h] = v + exs[h];
  }
  {
    float xn = b2f(xbf[(size_t)n * 64 + lane]);
#pragma unroll
    for (int h = 0; h < 4; h++) acc[h] += exs[h] * xn;
  }
#pragma unroll
  for (int h = 0; h < 4; h++) pbuf[wid][h * 64 + lane] = acc[h] / den[h];
  u16x4 ov;
#pragma unroll
  for (int jj = 0; jj < 4; jj++) ov[jj] = f2b(pbuf[wid][lane * 4 + jj]);
  *(u16x4*)(aggOut + (size_t)n * 256 + lane * 4) = ov;
}

// ---------------- gather (H=4) post-GEMM (inline logits, inline self) ----------------
template <int C, int CPL>
__global__ __launch_bounds__(256) void k_gather4(
    const int* __restrict__ rowStart, const int* __restrict__ csrSrc,
    const float* __restrict__ aeC, const float* __restrict__ asrc, const float* __restrict__ adst,
    const u16* __restrict__ hbuf, const float* __restrict__ bias,
    const float* __restrict__ bng, const float* __restrict__ bnb,
    const float* __restrict__ bnrm, const float* __restrict__ bnrv,
    u16* __restrict__ outbuf, int Nn) {
  constexpr int HC = 4 * C;
  typedef __attribute__((ext_vector_type(CPL))) unsigned short u16v;
  int wid = threadIdx.x >> 6;
  int n = blockIdx.x * 4 + wid;
  if (n >= Nn) return;
  int lane = threadIdx.x & 63;
  int hs = lane >> 4;
  __shared__ float pbuf[4][64 * 4];
  int r0 = rowStart[n], r1 = rowStart[n + 1];
  f32x4 vaN = *(const f32x4*)(asrc + n * 4);
  f32x4 vdN = *(const f32x4*)(adst + n * 4);

  f32x4 m = {-1e30f, -1e30f, -1e30f, -1e30f};
  f32x4 denl = {0.f, 0.f, 0.f, 0.f};
  f32x4 aes = {0.f, 0.f, 0.f, 0.f};
  float acc[CPL];
#pragma unroll
  for (int jj = 0; jj < CPL; jj++) acc[jj] = 0.f;

  const f32x4* AE4 = (const f32x4*)aeC;
  for (int base = r0; base < r1; base += 64) {
    int slot = base + lane;
    bool valid = slot < r1;
    int srcl = 0;
    f32x4 lg = {-1e30f, -1e30f, -1e30f, -1e30f};
    if (valid) {
      srcl = csrSrc[slot];
      f32x4 vaS = *(const f32x4*)(asrc + srcl * 4);
      f32x4 ae = AE4[slot];
#pragma unroll
      for (int h = 0; h < 4; h++) { aes[h] += ae[h]; lg[h] = leaky(vaS[h] + vdN[h] + ae[h]); }
    }
    f32x4 mc = lg;
#pragma unroll
    for (int off = 1; off < 64; off <<= 1) {
#pragma unroll
      for (int h = 0; h < 4; h++) mc[h] = fmaxf(mc[h], __shfl_xor(mc[h], off));
    }
    f32x4 rr;
#pragma unroll
    for (int h = 0; h < 4; h++) {
      float mn = fmaxf(m[h], mc[h]);
      rr[h] = __expf(m[h] - mn);
      m[h] = mn;
      denl[h] *= rr[h];
    }
    float rrh = sel4(rr, hs);
#pragma unroll
    for (int jj = 0; jj < CPL; jj++) acc[jj] *= rrh;
    f32x4 ex;
#pragma unroll
    for (int h = 0; h < 4; h++) ex[h] = valid ? __expf(lg[h] - m[h]) : 0.f;
#pragma unroll
    for (int h = 0; h < 4; h++) denl[h] += ex[h];
    *(f32x4*)(&pbuf[wid][lane * 4]) = ex;
    int nv = r1 - base; if (nv > 64) nv = 64;
    int j = 0;
    for (; j + 1 < nv; j += 2) {
      int s0 = __shfl(srcl, j);
      int s1 = __shfl(srcl, j + 1);
      float p0 = pbuf[wid][j * 4 + hs];
      float p1 = pbuf[wid][(j + 1) * 4 + hs];
      u16v h0 = *(const u16v*)(hbuf + (size_t)s0 * HC + lane * CPL);
      u16v h1 = *(const u16v*)(hbuf + (size_t)s1 * HC + lane * CPL);
#pragma unroll
      for (int jj = 0; jj < CPL; jj++) acc[jj] += p0 * b2f(h0[jj]) + p1 * b2f(h1[jj]);
    }
    if (j < nv) {
      int s0 = __shfl(srcl, j);
      float p0 = pbuf[wid][j * 4 + hs];
      u16v h0 = *(const u16v*)(hbuf + (size_t)s0 * HC + lane * CPL);
#pragma unroll
      for (int jj = 0; jj < CPL; jj++) acc[jj] += p0 * b2f(h0[jj]);
    }
  }
  float degf = fmaxf((float)(r1 - r0), 1.0f);
  f32x4 ls, exs, scv;
#pragma unroll
  for (int h = 0; h < 4; h++) {
    float a = aes[h];
#pragma unroll
    for (int off = 1; off < 64; off <<= 1) a += __shfl_xor(a, off);
    ls[h] = leaky(vaN[h] + vdN[h] + a / degf);
    float mn = fmaxf(m[h], ls[h]);
    scv[h] = __expf(m[h] - mn);
    m[h] = mn;
    denl[h] *= scv[h];
    exs[h] = __expf(ls[h] - mn);
  }
  float sch = sel4(scv, hs);
#pragma unroll
  for (int jj = 0; jj < CPL; jj++) acc[jj] *= sch;
  f32x4 den;
#pragma unroll
  for (int h = 0; h < 4; h++) {
    float v = denl[h];
#pragma unroll
    for (int off = 1; off < 64; off <<= 1) v += __shfl_xor(v, off);
    den[h] = v + exs[h];
  }
  {
    float ps = sel4(exs, hs);
    u16v hN = *(const u16v*)(hbuf + (size_t)n * HC + lane * CPL);
#pragma unroll
    for (int jj = 0; jj < CPL; jj++) acc[jj] += ps * b2f(hN[jj]);
  }
  float dh = sel4(den, hs);
  u16v ov;
#pragma unroll
  for (int jj = 0; jj < CPL; jj++) {
    int c = lane * CPL + jj;
    float v = acc[jj] / dh + bias[c];
    v = (v - bnrm[c]) * (bng[c] * rsqrtf(bnrv[c] + BN_EPS)) + bnb[c];
    ov[jj] = f2b(fmaxf(v, 0.f));
  }
  *(u16v*)(outbuf + (size_t)n * HC + lane * CPL) = ov;
}

// ---------------- gather (H=1, C=32), online single-pass ----------------
__global__ __launch_bounds__(256) void k_gather_L3(
    const int* __restrict__ rowStart, const int* __restrict__ csrSrc,
    const float* __restrict__ ae3, const float* __restrict__ asrc, const float* __restrict__ adst,
    const u16* __restrict__ hbuf, const float* __restrict__ bias,
    const float* __restrict__ bng, const float* __restrict__ bnb,
    const float* __restrict__ bnrm, const float* __restrict__ bnrv,
    u16* __restrict__ outbuf, int Nn) {
  int wid = threadIdx.x >> 6;
  int n = blockIdx.x * 4 + wid;
  if (n >= Nn) return;
  int lane = threadIdx.x & 63;
  int cl = lane & 31, half = lane >> 5;
  __shared__ float pbuf[4][64];
  int r0 = rowStart[n], r1 = rowStart[n + 1];
  float vaN = asrc[n], vdN = adst[n];

  float m = -1e30f, denl = 0.f, aes = 0.f, acc = 0.f;
  for (int base = r0; base < r1; base += 64) {
    int slot = base + lane;
    bool valid = slot < r1;
    int srcl = 0;
    float lg = -1e30f;
    if (valid) {
      srcl = csrSrc[slot];
      float ae = ae3[slot];
      aes += ae;
      lg = leaky(asrc[srcl] + vdN + ae);
    }
    float mc = lg;
#pragma unroll
    for (int off = 1; off < 64; off <<= 1) mc = fmaxf(mc, __shfl_xor(mc, off));
    float mn = fmaxf(m, mc);
    float sc = __expf(m - mn);
    m = mn;
    denl *= sc;
    acc *= sc;
    float ex = valid ? __expf(lg - m) : 0.f;
    denl += ex;
    pbuf[wid][lane] = ex;
    int nv = r1 - base; if (nv > 64) nv = 64;
    for (int j = half; j < nv; j += 2) {
      float p = pbuf[wid][j];
      int s = __shfl(srcl, j);
      acc += p * b2f(hbuf[(size_t)s * 32 + cl]);
    }
  }
  // self merge
#pragma unroll
  for (int off = 1; off < 64; off <<= 1) aes += __shfl_xor(aes, off);
  float degf = fmaxf((float)(r1 - r0), 1.0f);
  float ls = leaky(vaN + vdN + aes / degf);
  float mn = fmaxf(m, ls);
  float sc = __expf(m - mn);
  denl *= sc;
  acc *= sc;
  float exs = __expf(ls - mn);
#pragma unroll
  for (int off = 1; off < 64; off <<= 1) denl += __shfl_xor(denl, off);
  float den = denl + exs;
  if (half == 0) acc += exs * b2f(hbuf[(size_t)n * 32 + cl]);
  acc += __shfl_xor(acc, 32);
  if (half == 0) {
    float v = acc / den + bias[cl];
    v = (v - bnrm[cl]) * (bng[cl] * rsqrtf(bnrv[cl] + BN_EPS)) + bnb[cl];
    outbuf[(size_t)n * 32 + cl] = f2b(fmaxf(v, 0.f));
  }
}

// ---------------- fused pooling + MLP ----------------
__global__ __launch_bounds__(256) void k_pool_mlp(
    const u16* __restrict__ h3, const int* __restrict__ batch, int Nn,
    const float* __restrict__ lw1, const float* __restrict__ lb1,
    const float* __restrict__ lw2, const float* __restrict__ lb2,
    float* __restrict__ out) {
  int g = blockIdx.x;
  int tid = threadIdx.x;
  __shared__ int s_lo, s_hi;
  if (tid == 0) {
    int lo = 0, hi = Nn;
    while (lo < hi) { int mid = (lo + hi) >> 1; if (batch[mid] < g) lo = mid + 1; else hi = mid; }
    s_lo = lo;
    int lo2 = lo, hi2 = Nn;
    while (lo2 < hi2) { int mid = (lo2 + hi2) >> 1; if (batch[mid] < g + 1) lo2 = mid + 1; else hi2 = mid; }
    s_hi = lo2;
  }
  __syncthreads();
  int lo = s_lo, hi = s_hi;
  int c = tid & 31, r = tid >> 5;
  float sum = 0.f, mx = -1e30f;
  for (int n = lo + r; n < hi; n += 8) {
    float v = b2f(h3[(size_t)n * 32 + c]);
    sum += v;
    mx = fmaxf(mx, v);
  }
  __shared__ float ssum[8][32];
  __shared__ float smax[8][32];
  ssum[r][c] = sum;
  smax[r][c] = mx;
  __syncthreads();
  __shared__ float z[64];
  __shared__ float zz1[32];
  if (tid < 32) {
    float s = 0.f, m2 = -1e30f;
#pragma unroll
    for (int rr = 0; rr < 8; rr++) { s += ssum[rr][tid]; m2 = fmaxf(m2, smax[rr][tid]); }
    int cnt = hi - lo;
    z[tid] = s / fmaxf((float)cnt, 1.0f);
    z[32 + tid] = (cnt > 0) ? m2 : 0.f;
  }
  __syncthreads();
  if (tid < 32) {
    float s = lb1[tid];
    for (int k = 0; k < 64; k++) s += z[k] * lw1[k * 32 + tid];
    zz1[tid] = fmaxf(s, 0.f);
  }
  __syncthreads();
  if (tid == 0) {
    float s = lb2[0];
    for (int j = 0; j < 32; j++) s += zz1[j] * lw2[j];
    out[g] = 1.f / (1.f + expf(-s));
  }
}

// ---------------- driver ----------------
extern "C" void kernel_launch(void* const* d_in, const int* in_sizes, int n_in,
                              void* d_out, int out_size, void* d_ws, size_t ws_size,
                              hipStream_t stream) {
  const float* x     = (const float*)d_in[0];
  const int*   eidx  = (const int*)d_in[1];
  const float* eattr = (const float*)d_in[2];
  const int*   batch = (const int*)d_in[3];
  int N = in_sizes[0] / 64;
  int E = in_sizes[1] / 2;
  int NG = out_size;
  const int* src = eidx;
  const int* dst = eidx + E;

  const float* W[3]  = {(const float*)d_in[4],  (const float*)d_in[14], (const float*)d_in[24]};
  const float* AS[3] = {(const float*)d_in[5],  (const float*)d_in[15], (const float*)d_in[25]};
  const float* AD[3] = {(const float*)d_in[6],  (const float*)d_in[16], (const float*)d_in[26]};
  const float* WE[3] = {(const float*)d_in[7],  (const float*)d_in[17], (const float*)d_in[27]};
  const float* AE[3] = {(const float*)d_in[8],  (const float*)d_in[18], (const float*)d_in[28]};
  const float* B[3]  = {(const float*)d_in[9],  (const float*)d_in[19], (const float*)d_in[29]};
  const float* G[3]  = {(const float*)d_in[10], (const float*)d_in[20], (const float*)d_in[30]};
  const float* BT[3] = {(const float*)d_in[11], (const float*)d_in[21], (const float*)d_in[31]};
  const float* RM[3] = {(const float*)d_in[12], (const float*)d_in[22], (const float*)d_in[32]};
  const float* RV[3] = {(const float*)d_in[13], (const float*)d_in[23], (const float*)d_in[33]};
  const float* lw1 = (const float*)d_in[34];
  const float* lb1 = (const float*)d_in[35];
  const float* lw2 = (const float*)d_in[36];
  const float* lb2 = (const float*)d_in[37];

  char* wp = (char*)d_ws;
  auto alloc = [&](size_t bytes) -> void* {
    void* p = (void*)wp;
    wp += (bytes + 255) & ~(size_t)255;
    return p;
  };
  u16*   xbf      = (u16*)alloc((size_t)N * 64 * 2);
  u16*   aggB     = (u16*)alloc((size_t)N * 256 * 2);
  u16*   bufH     = (u16*)alloc((size_t)N * 512 * 2);
  u16*   bufA     = (u16*)alloc((size_t)N * 512 * 2);
  u16*   Wt1      = (u16*)alloc((size_t)512 * 64 * 2);
  u16*   Wt2      = (u16*)alloc((size_t)256 * 512 * 2);
  u16*   Wt3      = (u16*)alloc((size_t)32 * 256 * 2);
  int*   degInt   = (int*)alloc((size_t)N * 4);
  int*   cursor   = (int*)alloc((size_t)N * 4);
  int*   rowStart = (int*)alloc((size_t)(N + 1) * 4);
  int*   csrSrc   = (int*)alloc((size_t)E * 4);
  int*   posE     = (int*)alloc((size_t)E * 4);
  float* ae1      = (float*)alloc((size_t)E * 4 * 4);
  float* ae2      = (float*)alloc((size_t)E * 4 * 4);
  float* ae3buf   = (float*)alloc((size_t)E * 4);
  float* asrc     = (float*)alloc((size_t)N * 4 * 4);
  float* adst     = (float*)alloc((size_t)N * 4 * 4);
  float* watt1    = (float*)alloc(28 * 4);
  float* watt2    = (float*)alloc(28 * 4);
  float* watt3    = (float*)alloc(7 * 4);
  float* ws1      = (float*)alloc(64 * 4 * 4);
  float* wd1      = (float*)alloc(64 * 4 * 4);

  // ---- fused prep (weights + zero degInt/cursor)
  int prepTotal = 172352 + 2 * N;
  k_prep<<<(prepTotal + 255) / 256, 256, 0, stream>>>(
      W[0], W[1], W[2], AS[0], AD[0], WE[0], AE[0], WE[1], AE[1], WE[2], AE[2],
      Wt1, Wt2, Wt3, ws1, wd1, watt1, watt2, watt3, degInt, cursor, N);

  // ---- CSR build + one-pass edge-ae
  k_deg<<<(E + 255) / 256, 256, 0, stream>>>(dst, degInt, E);
  k_scan<<<1, 1024, 0, stream>>>(degInt, rowStart, N);
  k_fill_csr<<<(E + 255) / 256, 256, 0, stream>>>(src, dst, rowStart, cursor, csrSrc, posE, E);
  k_ae<<<(E + 255) / 256, 256, 0, stream>>>(eattr, posE, watt1, watt2, watt3, ae1, ae2, ae3buf, E);

  int gmM = (N + 127) / 128;
  int nb4 = (N + 3) / 4;

  // ---- layer 1: x-space aggregation, then 4 head-GEMMs with fused epilogue
  k_cast_attn_x<<<nb4, 256, 0, stream>>>(x, xbf, ws1, wd1, asrc, adst, N);
  k_gather_x<<<nb4, 256, 0, stream>>>(rowStart, csrSrc, ae1, asrc, adst, xbf, aggB, N);
  k_gemm_mfma<128, 128, 64, 64, true, 0><<<dim3(gmM, 1, 4), 256, 0, stream>>>(
      aggB, Wt1, bufA, N, 64, 128, 256, 512, 64, 128 * 64, 128,
      B[0], G[0], BT[0], RM[0], RV[0], nullptr, nullptr, nullptr, nullptr);

  // ---- layer 2: GEMM with fused attn dots (WN=64=C), then gather
  k_gemm_mfma<128, 128, 64, 64, false, 4><<<dim3(gmM, 2, 1), 256, 0, stream>>>(
      bufA, Wt2, bufH, N, 512, 256, 512, 256, 0, 0, 0,
      nullptr, nullptr, nullptr, nullptr, nullptr, AS[1], AD[1], asrc, adst);
  k_gather4<64, 4><<<nb4, 256, 0, stream>>>(rowStart, csrSrc, ae2, asrc, adst,
                                            bufH, B[1], G[1], BT[1], RM[1], RV[1], bufA, N);

  // ---- layer 3: GEMM with fused attn dots (WN=32=C, H=1), then gather
  k_gemm_mfma<128, 32, 32, 32, false, 1><<<dim3(gmM, 1, 1), 256, 0, stream>>>(
      bufA, Wt3, bufH, N, 256, 32, 256, 32, 0, 0, 0,
      nullptr, nullptr, nullptr, nullptr, nullptr, AS[2], AD[2], asrc, adst);
  k_gather_L3<<<nb4, 256, 0, stream>>>(rowStart, csrSrc, ae3buf, asrc, adst,
                                       bufH, B[2], G[2], BT[2], RM[2], RV[2], bufA, N);

  // ---- fused pooling + MLP
  k_pool_mlp<<<NG, 256, 0, stream>>>(bufA, batch, N, lw1, lb1, lw2, lb2, (float*)d_out);
}

// Round 9
// 256.604 us; speedup vs baseline: 1.3252x; 1.0339x over previous
//
#include <hip/hip_runtime.h>
#include <math.h>

#define NEG_SLOPE 0.2f
#define BN_EPS 1e-5f

typedef __attribute__((ext_vector_type(8))) short bf16x8;
typedef __attribute__((ext_vector_type(4))) float f32x4;
typedef unsigned short u16;
typedef __attribute__((ext_vector_type(4))) unsigned short u16x4;

static __device__ __forceinline__ float leaky(float v) { return v > 0.f ? v : NEG_SLOPE * v; }
static __device__ __forceinline__ float b2f(u16 b) { return __uint_as_float(((unsigned)b) << 16); }
static __device__ __forceinline__ u16 f2b(float f) {
  unsigned u = __float_as_uint(f);
  u += 0x7FFF + ((u >> 16) & 1);
  return (u16)(u >> 16);
}
static __device__ __forceinline__ float sel4(f32x4 v, int hs) {
  float a = (hs & 1) ? v[1] : v[0];
  float b = (hs & 1) ? v[3] : v[2];
  return (hs & 2) ? b : a;
}

// ---------------- fused prep: weight transposes + attn-weight projections + zero deg/cursor ----------------
__global__ void k_prep(const float* __restrict__ W1, const float* __restrict__ W2, const float* __restrict__ W3,
                       const float* __restrict__ AS1, const float* __restrict__ AD1,
                       const float* __restrict__ WE1, const float* __restrict__ AE1,
                       const float* __restrict__ WE2, const float* __restrict__ AE2,
                       const float* __restrict__ WE3, const float* __restrict__ AE3,
                       u16* __restrict__ Wt1, u16* __restrict__ Wt2, u16* __restrict__ Wt3,
                       float* __restrict__ ws1, float* __restrict__ wd1,
                       float* __restrict__ watt1, float* __restrict__ watt2, float* __restrict__ watt3,
                       int* __restrict__ degInt, int* __restrict__ cursor, int Nn) {
  int idx = blockIdx.x * blockDim.x + threadIdx.x;
  if (idx < 32768) {                       // Wt1 [512][64] <- W1 [64][512]
    int k = idx >> 9, n = idx & 511;
    Wt1[n * 64 + k] = f2b(W1[idx]);
  } else if (idx < 163840) {               // Wt2 [256][512] <- W2 [512][256]
    int i = idx - 32768;
    int k = i >> 8, n = i & 255;
    Wt2[n * 512 + k] = f2b(W2[i]);
  } else if (idx < 172032) {               // Wt3 [32][256] <- W3 [256][32]
    int i = idx - 163840;
    int k = i >> 5, n = i & 31;
    Wt3[n * 256 + k] = f2b(W3[i]);
  } else if (idx < 172288) {               // ws1/wd1 [64][4]
    int t = idx - 172032;
    int k = t >> 2, h = t & 3;
    float s1 = 0.f, s2 = 0.f;
    for (int c = 0; c < 128; c++) {
      float w = W1[k * 512 + h * 128 + c];
      s1 += w * AS1[h * 128 + c];
      s2 += w * AD1[h * 128 + c];
    }
    ws1[t] = s1; wd1[t] = s2;
  } else if (idx < 172316) {               // watt1 [7][4]
    int t = idx - 172288;
    int d = t >> 2, h = t & 3;
    float s = 0.f;
    for (int c = 0; c < 128; c++) s += WE1[d * 512 + h * 128 + c] * AE1[h * 128 + c];
    watt1[t] = s;
  } else if (idx < 172344) {               // watt2 [7][4]
    int t = idx - 172316;
    int d = t >> 2, h = t & 3;
    float s = 0.f;
    for (int c = 0; c < 64; c++) s += WE2[d * 256 + h * 64 + c] * AE2[h * 64 + c];
    watt2[t] = s;
  } else if (idx < 172351) {               // watt3 [7]
    int d = idx - 172344;
    float s = 0.f;
    for (int c = 0; c < 32; c++) s += WE3[d * 32 + c] * AE3[c];
    watt3[d] = s;
  } else if (idx >= 172352 && idx < 172352 + Nn) {
    degInt[idx - 172352] = 0;
  } else if (idx >= 172352 + Nn && idx < 172352 + 2 * Nn) {
    cursor[idx - 172352 - Nn] = 0;
  }
}

// ---------------- CSR build ----------------
__global__ void k_deg(const int* __restrict__ dst, int* __restrict__ degInt, int E) {
  int e = blockIdx.x * blockDim.x + threadIdx.x;
  if (e < E) atomicAdd(&degInt[dst[e]], 1);
}

__global__ void k_scan(const int* __restrict__ degInt, int* __restrict__ rowStart, int n) {
  __shared__ int sums[1024];
  int tid = threadIdx.x;
  int per = (n + 1023) / 1024;
  int start = tid * per;
  int end = start + per; if (end > n) end = n;
  int s = 0;
  for (int i = start; i < end; i++) s += degInt[i];
  sums[tid] = s;
  __syncthreads();
  for (int off = 1; off < 1024; off <<= 1) {
    int v = (tid >= off) ? sums[tid - off] : 0;
    __syncthreads();
    sums[tid] += v;
    __syncthreads();
  }
  int base = (tid > 0) ? sums[tid - 1] : 0;
  for (int i = start; i < end; i++) { rowStart[i] = base; base += degInt[i]; }
  if (tid == 1023) rowStart[n] = sums[1023];
}

// fill CSR AND scatter all 9 head ae-slots in one edge pass (pos is local -> no posE buffer)
__global__ void k_fill_csr_ae(const int* __restrict__ src, const int* __restrict__ dst,
                              const float* __restrict__ eattr,
                              const int* __restrict__ rowStart, int* __restrict__ cursor,
                              int* __restrict__ csrSrc,
                              const float* __restrict__ watt1, const float* __restrict__ watt2,
                              const float* __restrict__ watt3,
                              float* __restrict__ ae1, float* __restrict__ ae2,
                              float* __restrict__ ae3, int E) {
  int e = blockIdx.x * blockDim.x + threadIdx.x;
  if (e >= E) return;
  int d = dst[e];
  int pos = rowStart[d] + atomicAdd(&cursor[d], 1);
  csrSrc[pos] = src[e];
  float ea[7];
#pragma unroll
  for (int dd = 0; dd < 7; dd++) ea[dd] = eattr[e * 7 + dd];
  f32x4 o1, o2;
#pragma unroll
  for (int h = 0; h < 4; h++) {
    float a1 = 0.f, a2 = 0.f;
#pragma unroll
    for (int dd = 0; dd < 7; dd++) { a1 += ea[dd] * watt1[dd * 4 + h]; a2 += ea[dd] * watt2[dd * 4 + h]; }
    o1[h] = a1; o2[h] = a2;
  }
  float a3 = 0.f;
#pragma unroll
  for (int dd = 0; dd < 7; dd++) a3 += ea[dd] * watt3[dd];
  *(f32x4*)(ae1 + (size_t)pos * 4) = o1;
  *(f32x4*)(ae2 + (size_t)pos * 4) = o2;
  ae3[pos] = a3;
}

// ---------------- fused x cast + L1 attention dots ----------------
__global__ __launch_bounds__(256) void k_cast_attn_x(const float* __restrict__ x, u16* __restrict__ xbf,
                                                     const float* __restrict__ ws, const float* __restrict__ wd,
                                                     float* __restrict__ asrc, float* __restrict__ adst, int Nn) {
  int n = blockIdx.x * 4 + (threadIdx.x >> 6);
  if (n >= Nn) return;
  int lane = threadIdx.x & 63;
  float xv = x[(size_t)n * 64 + lane];
  xbf[(size_t)n * 64 + lane] = f2b(xv);
  f32x4 vs = *(const f32x4*)(ws + lane * 4);
  f32x4 vd = *(const f32x4*)(wd + lane * 4);
  f32x4 s1, s2;
#pragma unroll
  for (int h = 0; h < 4; h++) { s1[h] = xv * vs[h]; s2[h] = xv * vd[h]; }
#pragma unroll
  for (int off = 1; off < 64; off <<= 1) {
#pragma unroll
    for (int h = 0; h < 4; h++) { s1[h] += __shfl_xor(s1[h], off); s2[h] += __shfl_xor(s2[h], off); }
  }
  if (lane == 0) {
    *(f32x4*)(asrc + n * 4) = s1;
    *(f32x4*)(adst + n * 4) = s2;
  }
}

// ---------------- MFMA bf16 GEMM with optional epilogue / fused attn dots ----------------
template <int BM, int BN, int WM, int WN, bool EPI, int ATTN_H>
__global__ __launch_bounds__(256) void k_gemm_mfma(const u16* __restrict__ A,
                                                   const u16* __restrict__ Bt,
                                                   u16* __restrict__ Cout,
                                                   int M, int K, int Nc, int lda, int ldc,
                                                   int AzOff, int BzOff, int CzOff,
                                                   const float* __restrict__ bias,
                                                   const float* __restrict__ bng,
                                                   const float* __restrict__ bnb,
                                                   const float* __restrict__ bnrm,
                                                   const float* __restrict__ bnrv,
                                                   const float* __restrict__ a_s,
                                                   const float* __restrict__ a_d,
                                                   float* __restrict__ asrc,
                                                   float* __restrict__ adst) {
  constexpr int BK = 64;
  constexpr int LDT = BK + 8;
  __shared__ u16 As[BM][LDT];
  __shared__ u16 Bs[BN][LDT];
  constexpr int NWN = BN / WN;
  constexpr int M_REP = WM / 16;
  constexpr int N_REP = WN / 16;
  int z = blockIdx.z;
  A += (size_t)z * AzOff;
  Bt += (size_t)z * BzOff;
  Cout += (size_t)z * CzOff;
  if (EPI) {
    bias += (size_t)z * CzOff; bng += (size_t)z * CzOff; bnb += (size_t)z * CzOff;
    bnrm += (size_t)z * CzOff; bnrv += (size_t)z * CzOff;
  }
  int tid = threadIdx.x;
  int wid = tid >> 6, lane = tid & 63;
  int wr = wid / NWN, wc = wid % NWN;
  int bm = blockIdx.x * BM, bn = blockIdx.y * BN;
  int l15 = lane & 15, l4 = lane >> 4;

  f32x4 acc[M_REP][N_REP];
#pragma unroll
  for (int m = 0; m < M_REP; m++)
#pragma unroll
    for (int n = 0; n < N_REP; n++) acc[m][n] = (f32x4){0.f, 0.f, 0.f, 0.f};

  for (int k0 = 0; k0 < K; k0 += BK) {
    constexpr int CHA = BM * BK / 8;
#pragma unroll
    for (int ch0 = 0; ch0 < CHA; ch0 += 256) {
      int ch = ch0 + tid;
      int row = ch >> 3, cc = (ch & 7) * 8;
      int gr = bm + row;
      bf16x8 v = {};
      if (gr < M) v = *(const bf16x8*)(A + (size_t)gr * lda + k0 + cc);
      *(bf16x8*)(&As[row][cc]) = v;
    }
    constexpr int CHB = BN * BK / 8;
#pragma unroll
    for (int ch0 = 0; ch0 < CHB; ch0 += 256) {
      int ch = ch0 + tid;
      int row = ch >> 3, cc = (ch & 7) * 8;
      int gr = bn + row;
      bf16x8 v = {};
      if (gr < Nc) v = *(const bf16x8*)(Bt + (size_t)gr * K + k0 + cc);
      *(bf16x8*)(&Bs[row][cc]) = v;
    }
    __syncthreads();
#pragma unroll
    for (int ks = 0; ks < BK; ks += 32) {
      bf16x8 af[M_REP], bfr[N_REP];
#pragma unroll
      for (int m = 0; m < M_REP; m++)
        af[m] = *(const bf16x8*)(&As[wr * WM + m * 16 + l15][ks + l4 * 8]);
#pragma unroll
      for (int n = 0; n < N_REP; n++)
        bfr[n] = *(const bf16x8*)(&Bs[wc * WN + n * 16 + l15][ks + l4 * 8]);
#pragma unroll
      for (int m = 0; m < M_REP; m++)
#pragma unroll
        for (int n = 0; n < N_REP; n++)
          acc[m][n] = __builtin_amdgcn_mfma_f32_16x16x32_bf16(af[m], bfr[n], acc[m][n], 0, 0, 0);
    }
    __syncthreads();
  }
#pragma unroll
  for (int m = 0; m < M_REP; m++) {
#pragma unroll
    for (int r = 0; r < 4; r++) {
      int grow = bm + wr * WM + m * 16 + l4 * 4 + r;
      if (grow >= M) continue;
#pragma unroll
      for (int n = 0; n < N_REP; n++) {
        int gcol = bn + wc * WN + n * 16 + l15;
        if (gcol >= Nc) continue;
        float v = acc[m][n][r];
        if (EPI) {
          v += bias[gcol];
          v = (v - bnrm[gcol]) * (bng[gcol] * rsqrtf(bnrv[gcol] + BN_EPS)) + bnb[gcol];
          v = fmaxf(v, 0.f);
        }
        Cout[(size_t)grow * ldc + gcol] = f2b(v);
      }
    }
  }
  if (ATTN_H > 0) {
    int h = blockIdx.y * NWN + wc;
#pragma unroll
    for (int m = 0; m < M_REP; m++) {
#pragma unroll
      for (int r = 0; r < 4; r++) {
        float s1 = 0.f, s2 = 0.f;
#pragma unroll
        for (int n = 0; n < N_REP; n++) {
          float av = acc[m][n][r];
          int cc = n * 16 + l15;
          s1 += av * a_s[h * WN + cc];
          s2 += av * a_d[h * WN + cc];
        }
#pragma unroll
        for (int off = 1; off < 16; off <<= 1) { s1 += __shfl_xor(s1, off); s2 += __shfl_xor(s2, off); }
        int grow = bm + wr * WM + m * 16 + l4 * 4 + r;
        if (l15 == 0 && grow < M) {
          asrc[grow * ATTN_H + h] = s1;
          adst[grow * ATTN_H + h] = s2;
        }
      }
    }
  }
}

// ---------------- L1 gather in x-space (inline logits, inline self via mean-ae) ----------------
__global__ __launch_bounds__(256) void k_gather_x(
    const int* __restrict__ rowStart, const int* __restrict__ csrSrc,
    const float* __restrict__ aeC, const float* __restrict__ asrc, const float* __restrict__ adst,
    const u16* __restrict__ xbf, u16* __restrict__ aggOut, int Nn) {
  int wid = threadIdx.x >> 6;
  int n = blockIdx.x * 4 + wid;
  if (n >= Nn) return;
  int lane = threadIdx.x & 63;
  __shared__ float pbuf[4][64 * 4];
  int r0 = rowStart[n], r1 = rowStart[n + 1];
  f32x4 vaN = *(const f32x4*)(asrc + n * 4);
  f32x4 vdN = *(const f32x4*)(adst + n * 4);

  f32x4 m = {-1e30f, -1e30f, -1e30f, -1e30f};
  f32x4 denl = {0.f, 0.f, 0.f, 0.f};
  f32x4 aes = {0.f, 0.f, 0.f, 0.f};
  f32x4 acc = {0.f, 0.f, 0.f, 0.f};

  const f32x4* AE4 = (const f32x4*)aeC;
  for (int base = r0; base < r1; base += 64) {
    int slot = base + lane;
    bool valid = slot < r1;
    int srcl = 0;
    f32x4 lg = {-1e30f, -1e30f, -1e30f, -1e30f};
    if (valid) {
      srcl = csrSrc[slot];
      f32x4 vaS = *(const f32x4*)(asrc + srcl * 4);
      f32x4 ae = AE4[slot];
#pragma unroll
      for (int h = 0; h < 4; h++) { aes[h] += ae[h]; lg[h] = leaky(vaS[h] + vdN[h] + ae[h]); }
    }
    f32x4 mc = lg;
#pragma unroll
    for (int off = 1; off < 64; off <<= 1) {
#pragma unroll
      for (int h = 0; h < 4; h++) mc[h] = fmaxf(mc[h], __shfl_xor(mc[h], off));
    }
    f32x4 rr;
#pragma unroll
    for (int h = 0; h < 4; h++) {
      float mn = fmaxf(m[h], mc[h]);
      rr[h] = __expf(m[h] - mn);
      m[h] = mn;
      denl[h] *= rr[h];
      acc[h] *= rr[h];
    }
    f32x4 ex;
#pragma unroll
    for (int h = 0; h < 4; h++) ex[h] = valid ? __expf(lg[h] - m[h]) : 0.f;
#pragma unroll
    for (int h = 0; h < 4; h++) denl[h] += ex[h];
    *(f32x4*)(&pbuf[wid][lane * 4]) = ex;
    int nv = r1 - base; if (nv > 64) nv = 64;
    int j = 0;
    for (; j + 3 < nv; j += 4) {
      int s0 = __shfl(srcl, j);
      int s1 = __shfl(srcl, j + 1);
      int s2 = __shfl(srcl, j + 2);
      int s3 = __shfl(srcl, j + 3);
      f32x4 p0 = *(const f32x4*)(&pbuf[wid][j * 4]);
      f32x4 p1 = *(const f32x4*)(&pbuf[wid][(j + 1) * 4]);
      f32x4 p2 = *(const f32x4*)(&pbuf[wid][(j + 2) * 4]);
      f32x4 p3 = *(const f32x4*)(&pbuf[wid][(j + 3) * 4]);
      float x0 = b2f(xbf[(size_t)s0 * 64 + lane]);
      float x1 = b2f(xbf[(size_t)s1 * 64 + lane]);
      float x2 = b2f(xbf[(size_t)s2 * 64 + lane]);
      float x3 = b2f(xbf[(size_t)s3 * 64 + lane]);
#pragma unroll
      for (int h = 0; h < 4; h++)
        acc[h] += p0[h] * x0 + p1[h] * x1 + p2[h] * x2 + p3[h] * x3;
    }
    for (; j < nv; j++) {
      int s0 = __shfl(srcl, j);
      f32x4 p0 = *(const f32x4*)(&pbuf[wid][j * 4]);
      float x0 = b2f(xbf[(size_t)s0 * 64 + lane]);
#pragma unroll
      for (int h = 0; h < 4; h++) acc[h] += p0[h] * x0;
    }
  }
  float degf = fmaxf((float)(r1 - r0), 1.0f);
  f32x4 ls, exs;
#pragma unroll
  for (int h = 0; h < 4; h++) {
    float a = aes[h];
#pragma unroll
    for (int off = 1; off < 64; off <<= 1) a += __shfl_xor(a, off);
    ls[h] = leaky(vaN[h] + vdN[h] + a / degf);
    float mn = fmaxf(m[h], ls[h]);
    float sc = __expf(m[h] - mn);
    m[h] = mn;
    denl[h] *= sc;
    acc[h] *= sc;
    exs[h] = __expf(ls[h] - mn);
  }
  f32x4 den;
#pragma unroll
  for (int h = 0; h < 4; h++) {
    float v = denl[h];
#pragma unroll
    for (int off = 1; off < 64; off <<= 1) v += __shfl_xor(v, off);
    den[h] = v + exs[h];
  }
  {
    float xn = b2f(xbf[(size_t)n * 64 + lane]);
#pragma unroll
    for (int h = 0; h < 4; h++) acc[h] += exs[h] * xn;
  }
#pragma unroll
  for (int h = 0; h < 4; h++) pbuf[wid][h * 64 + lane] = acc[h] / den[h];
  u16x4 ov;
#pragma unroll
  for (int jj = 0; jj < 4; jj++) ov[jj] = f2b(pbuf[wid][lane * 4 + jj]);
  *(u16x4*)(aggOut + (size_t)n * 256 + lane * 4) = ov;
}

// ---------------- gather (H=4) post-GEMM (inline logits, inline self) ----------------
template <int C, int CPL>
__global__ __launch_bounds__(256) void k_gather4(
    const int* __restrict__ rowStart, const int* __restrict__ csrSrc,
    const float* __restrict__ aeC, const float* __restrict__ asrc, const float* __restrict__ adst,
    const u16* __restrict__ hbuf, const float* __restrict__ bias,
    const float* __restrict__ bng, const float* __restrict__ bnb,
    const float* __restrict__ bnrm, const float* __restrict__ bnrv,
    u16* __restrict__ outbuf, int Nn) {
  constexpr int HC = 4 * C;
  typedef __attribute__((ext_vector_type(CPL))) unsigned short u16v;
  int wid = threadIdx.x >> 6;
  int n = blockIdx.x * 4 + wid;
  if (n >= Nn) return;
  int lane = threadIdx.x & 63;
  int hs = lane >> 4;
  __shared__ float pbuf[4][64 * 4];
  int r0 = rowStart[n], r1 = rowStart[n + 1];
  f32x4 vaN = *(const f32x4*)(asrc + n * 4);
  f32x4 vdN = *(const f32x4*)(adst + n * 4);

  f32x4 m = {-1e30f, -1e30f, -1e30f, -1e30f};
  f32x4 denl = {0.f, 0.f, 0.f, 0.f};
  f32x4 aes = {0.f, 0.f, 0.f, 0.f};
  float acc[CPL];
#pragma unroll
  for (int jj = 0; jj < CPL; jj++) acc[jj] = 0.f;

  const f32x4* AE4 = (const f32x4*)aeC;
  for (int base = r0; base < r1; base += 64) {
    int slot = base + lane;
    bool valid = slot < r1;
    int srcl = 0;
    f32x4 lg = {-1e30f, -1e30f, -1e30f, -1e30f};
    if (valid) {
      srcl = csrSrc[slot];
      f32x4 vaS = *(const f32x4*)(asrc + srcl * 4);
      f32x4 ae = AE4[slot];
#pragma unroll
      for (int h = 0; h < 4; h++) { aes[h] += ae[h]; lg[h] = leaky(vaS[h] + vdN[h] + ae[h]); }
    }
    f32x4 mc = lg;
#pragma unroll
    for (int off = 1; off < 64; off <<= 1) {
#pragma unroll
      for (int h = 0; h < 4; h++) mc[h] = fmaxf(mc[h], __shfl_xor(mc[h], off));
    }
    f32x4 rr;
#pragma unroll
    for (int h = 0; h < 4; h++) {
      float mn = fmaxf(m[h], mc[h]);
      rr[h] = __expf(m[h] - mn);
      m[h] = mn;
      denl[h] *= rr[h];
    }
    float rrh = sel4(rr, hs);
#pragma unroll
    for (int jj = 0; jj < CPL; jj++) acc[jj] *= rrh;
    f32x4 ex;
#pragma unroll
    for (int h = 0; h < 4; h++) ex[h] = valid ? __expf(lg[h] - m[h]) : 0.f;
#pragma unroll
    for (int h = 0; h < 4; h++) denl[h] += ex[h];
    *(f32x4*)(&pbuf[wid][lane * 4]) = ex;
    int nv = r1 - base; if (nv > 64) nv = 64;
    int j = 0;
    for (; j + 3 < nv; j += 4) {
      int s0 = __shfl(srcl, j);
      int s1 = __shfl(srcl, j + 1);
      int s2 = __shfl(srcl, j + 2);
      int s3 = __shfl(srcl, j + 3);
      float p0 = pbuf[wid][j * 4 + hs];
      float p1 = pbuf[wid][(j + 1) * 4 + hs];
      float p2 = pbuf[wid][(j + 2) * 4 + hs];
      float p3 = pbuf[wid][(j + 3) * 4 + hs];
      u16v h0 = *(const u16v*)(hbuf + (size_t)s0 * HC + lane * CPL);
      u16v h1 = *(const u16v*)(hbuf + (size_t)s1 * HC + lane * CPL);
      u16v h2 = *(const u16v*)(hbuf + (size_t)s2 * HC + lane * CPL);
      u16v h3 = *(const u16v*)(hbuf + (size_t)s3 * HC + lane * CPL);
#pragma unroll
      for (int jj = 0; jj < CPL; jj++)
        acc[jj] += p0 * b2f(h0[jj]) + p1 * b2f(h1[jj]) + p2 * b2f(h2[jj]) + p3 * b2f(h3[jj]);
    }
    for (; j < nv; j++) {
      int s0 = __shfl(srcl, j);
      float p0 = pbuf[wid][j * 4 + hs];
      u16v h0 = *(const u16v*)(hbuf + (size_t)s0 * HC + lane * CPL);
#pragma unroll
      for (int jj = 0; jj < CPL; jj++) acc[jj] += p0 * b2f(h0[jj]);
    }
  }
  float degf = fmaxf((float)(r1 - r0), 1.0f);
  f32x4 ls, exs, scv;
#pragma unroll
  for (int h = 0; h < 4; h++) {
    float a = aes[h];
#pragma unroll
    for (int off = 1; off < 64; off <<= 1) a += __shfl_xor(a, off);
    ls[h] = leaky(vaN[h] + vdN[h] + a / degf);
    float mn = fmaxf(m[h], ls[h]);
    scv[h] = __expf(m[h] - mn);
    m[h] = mn;
    denl[h] *= scv[h];
    exs[h] = __expf(ls[h] - mn);
  }
  float sch = sel4(scv, hs);
#pragma unroll
  for (int jj = 0; jj < CPL; jj++) acc[jj] *= sch;
  f32x4 den;
#pragma unroll
  for (int h = 0; h < 4; h++) {
    float v = denl[h];
#pragma unroll
    for (int off = 1; off < 64; off <<= 1) v += __shfl_xor(v, off);
    den[h] = v + exs[h];
  }
  {
    float ps = sel4(exs, hs);
    u16v hN = *(const u16v*)(hbuf + (size_t)n * HC + lane * CPL);
#pragma unroll
    for (int jj = 0; jj < CPL; jj++) acc[jj] += ps * b2f(hN[jj]);
  }
  float dh = sel4(den, hs);
  u16v ov;
#pragma unroll
  for (int jj = 0; jj < CPL; jj++) {
    int c = lane * CPL + jj;
    float v = acc[jj] / dh + bias[c];
    v = (v - bnrm[c]) * (bng[c] * rsqrtf(bnrv[c] + BN_EPS)) + bnb[c];
    ov[jj] = f2b(fmaxf(v, 0.f));
  }
  *(u16v*)(outbuf + (size_t)n * HC + lane * CPL) = ov;
}

// ---------------- gather (H=1, C=32), online single-pass ----------------
__global__ __launch_bounds__(256) void k_gather_L3(
    const int* __restrict__ rowStart, const int* __restrict__ csrSrc,
    const float* __restrict__ ae3, const float* __restrict__ asrc, const float* __restrict__ adst,
    const u16* __restrict__ hbuf, const float* __restrict__ bias,
    const float* __restrict__ bng, const float* __restrict__ bnb,
    const float* __restrict__ bnrm, const float* __restrict__ bnrv,
    u16* __restrict__ outbuf, int Nn) {
  int wid = threadIdx.x >> 6;
  int n = blockIdx.x * 4 + wid;
  if (n >= Nn) return;
  int lane = threadIdx.x & 63;
  int cl = lane & 31, half = lane >> 5;
  __shared__ float pbuf[4][64];
  int r0 = rowStart[n], r1 = rowStart[n + 1];
  float vaN = asrc[n], vdN = adst[n];

  float m = -1e30f, denl = 0.f, aes = 0.f, acc = 0.f;
  for (int base = r0; base < r1; base += 64) {
    int slot = base + lane;
    bool valid = slot < r1;
    int srcl = 0;
    float lg = -1e30f;
    if (valid) {
      srcl = csrSrc[slot];
      float ae = ae3[slot];
      aes += ae;
      lg = leaky(asrc[srcl] + vdN + ae);
    }
    float mc = lg;
#pragma unroll
    for (int off = 1; off < 64; off <<= 1) mc = fmaxf(mc, __shfl_xor(mc, off));
    float mn = fmaxf(m, mc);
    float sc = __expf(m - mn);
    m = mn;
    denl *= sc;
    acc *= sc;
    float ex = valid ? __expf(lg - m) : 0.f;
    denl += ex;
    pbuf[wid][lane] = ex;
    int nv = r1 - base; if (nv > 64) nv = 64;
    for (int j = half; j < nv; j += 2) {
      float p = pbuf[wid][j];
      int s = __shfl(srcl, j);
      acc += p * b2f(hbuf[(size_t)s * 32 + cl]);
    }
  }
#pragma unroll
  for (int off = 1; off < 64; off <<= 1) aes += __shfl_xor(aes, off);
  float degf = fmaxf((float)(r1 - r0), 1.0f);
  float ls = leaky(vaN + vdN + aes / degf);
  float mn = fmaxf(m, ls);
  float sc = __expf(m - mn);
  denl *= sc;
  acc *= sc;
  float exs = __expf(ls - mn);
#pragma unroll
  for (int off = 1; off < 64; off <<= 1) denl += __shfl_xor(denl, off);
  float den = denl + exs;
  if (half == 0) acc += exs * b2f(hbuf[(size_t)n * 32 + cl]);
  acc += __shfl_xor(acc, 32);
  if (half == 0) {
    float v = acc / den + bias[cl];
    v = (v - bnrm[cl]) * (bng[cl] * rsqrtf(bnrv[cl] + BN_EPS)) + bnb[cl];
    outbuf[(size_t)n * 32 + cl] = f2b(fmaxf(v, 0.f));
  }
}

// ---------------- fused pooling + MLP ----------------
__global__ __launch_bounds__(256) void k_pool_mlp(
    const u16* __restrict__ h3, const int* __restrict__ batch, int Nn,
    const float* __restrict__ lw1, const float* __restrict__ lb1,
    const float* __restrict__ lw2, const float* __restrict__ lb2,
    float* __restrict__ out) {
  int g = blockIdx.x;
  int tid = threadIdx.x;
  __shared__ int s_lo, s_hi;
  if (tid == 0) {
    int lo = 0, hi = Nn;
    while (lo < hi) { int mid = (lo + hi) >> 1; if (batch[mid] < g) lo = mid + 1; else hi = mid; }
    s_lo = lo;
    int lo2 = lo, hi2 = Nn;
    while (lo2 < hi2) { int mid = (lo2 + hi2) >> 1; if (batch[mid] < g + 1) lo2 = mid + 1; else hi2 = mid; }
    s_hi = lo2;
  }
  __syncthreads();
  int lo = s_lo, hi = s_hi;
  int c = tid & 31, r = tid >> 5;
  float sum = 0.f, mx = -1e30f;
  for (int n = lo + r; n < hi; n += 8) {
    float v = b2f(h3[(size_t)n * 32 + c]);
    sum += v;
    mx = fmaxf(mx, v);
  }
  __shared__ float ssum[8][32];
  __shared__ float smax[8][32];
  ssum[r][c] = sum;
  smax[r][c] = mx;
  __syncthreads();
  __shared__ float z[64];
  __shared__ float zz1[32];
  if (tid < 32) {
    float s = 0.f, m2 = -1e30f;
#pragma unroll
    for (int rr = 0; rr < 8; rr++) { s += ssum[rr][tid]; m2 = fmaxf(m2, smax[rr][tid]); }
    int cnt = hi - lo;
    z[tid] = s / fmaxf((float)cnt, 1.0f);
    z[32 + tid] = (cnt > 0) ? m2 : 0.f;
  }
  __syncthreads();
  if (tid < 32) {
    float s = lb1[tid];
    for (int k = 0; k < 64; k++) s += z[k] * lw1[k * 32 + tid];
    zz1[tid] = fmaxf(s, 0.f);
  }
  __syncthreads();
  if (tid == 0) {
    float s = lb2[0];
    for (int j = 0; j < 32; j++) s += zz1[j] * lw2[j];
    out[g] = 1.f / (1.f + expf(-s));
  }
}

// ---------------- driver ----------------
extern "C" void kernel_launch(void* const* d_in, const int* in_sizes, int n_in,
                              void* d_out, int out_size, void* d_ws, size_t ws_size,
                              hipStream_t stream) {
  const float* x     = (const float*)d_in[0];
  const int*   eidx  = (const int*)d_in[1];
  const float* eattr = (const float*)d_in[2];
  const int*   batch = (const int*)d_in[3];
  int N = in_sizes[0] / 64;
  int E = in_sizes[1] / 2;
  int NG = out_size;
  const int* src = eidx;
  const int* dst = eidx + E;

  const float* W[3]  = {(const float*)d_in[4],  (const float*)d_in[14], (const float*)d_in[24]};
  const float* AS[3] = {(const float*)d_in[5],  (const float*)d_in[15], (const float*)d_in[25]};
  const float* AD[3] = {(const float*)d_in[6],  (const float*)d_in[16], (const float*)d_in[26]};
  const float* WE[3] = {(const float*)d_in[7],  (const float*)d_in[17], (const float*)d_in[27]};
  const float* AE[3] = {(const float*)d_in[8],  (const float*)d_in[18], (const float*)d_in[28]};
  const float* B[3]  = {(const float*)d_in[9],  (const float*)d_in[19], (const float*)d_in[29]};
  const float* G[3]  = {(const float*)d_in[10], (const float*)d_in[20], (const float*)d_in[30]};
  const float* BT[3] = {(const float*)d_in[11], (const float*)d_in[21], (const float*)d_in[31]};
  const float* RM[3] = {(const float*)d_in[12], (const float*)d_in[22], (const float*)d_in[32]};
  const float* RV[3] = {(const float*)d_in[13], (const float*)d_in[23], (const float*)d_in[33]};
  const float* lw1 = (const float*)d_in[34];
  const float* lb1 = (const float*)d_in[35];
  const float* lw2 = (const float*)d_in[36];
  const float* lb2 = (const float*)d_in[37];

  char* wp = (char*)d_ws;
  auto alloc = [&](size_t bytes) -> void* {
    void* p = (void*)wp;
    wp += (bytes + 255) & ~(size_t)255;
    return p;
  };
  u16*   xbf      = (u16*)alloc((size_t)N * 64 * 2);
  u16*   aggB     = (u16*)alloc((size_t)N * 256 * 2);
  u16*   bufH     = (u16*)alloc((size_t)N * 512 * 2);
  u16*   bufA     = (u16*)alloc((size_t)N * 512 * 2);
  u16*   Wt1      = (u16*)alloc((size_t)512 * 64 * 2);
  u16*   Wt2      = (u16*)alloc((size_t)256 * 512 * 2);
  u16*   Wt3      = (u16*)alloc((size_t)32 * 256 * 2);
  int*   degInt   = (int*)alloc((size_t)N * 4);
  int*   cursor   = (int*)alloc((size_t)N * 4);
  int*   rowStart = (int*)alloc((size_t)(N + 1) * 4);
  int*   csrSrc   = (int*)alloc((size_t)E * 4);
  float* ae1      = (float*)alloc((size_t)E * 4 * 4);
  float* ae2      = (float*)alloc((size_t)E * 4 * 4);
  float* ae3buf   = (float*)alloc((size_t)E * 4);
  float* asrc     = (float*)alloc((size_t)N * 4 * 4);
  float* adst     = (float*)alloc((size_t)N * 4 * 4);
  float* watt1    = (float*)alloc(28 * 4);
  float* watt2    = (float*)alloc(28 * 4);
  float* watt3    = (float*)alloc(7 * 4);
  float* ws1      = (float*)alloc(64 * 4 * 4);
  float* wd1      = (float*)alloc(64 * 4 * 4);

  // ---- fused prep (weights + zero degInt/cursor)
  int prepTotal = 172352 + 2 * N;
  k_prep<<<(prepTotal + 255) / 256, 256, 0, stream>>>(
      W[0], W[1], W[2], AS[0], AD[0], WE[0], AE[0], WE[1], AE[1], WE[2], AE[2],
      Wt1, Wt2, Wt3, ws1, wd1, watt1, watt2, watt3, degInt, cursor, N);

  // ---- CSR build + fused edge-ae scatter
  k_deg<<<(E + 255) / 256, 256, 0, stream>>>(dst, degInt, E);
  k_scan<<<1, 1024, 0, stream>>>(degInt, rowStart, N);
  k_fill_csr_ae<<<(E + 255) / 256, 256, 0, stream>>>(src, dst, eattr, rowStart, cursor, csrSrc,
                                                     watt1, watt2, watt3, ae1, ae2, ae3buf, E);

  int gmM = (N + 127) / 128;
  int nb4 = (N + 3) / 4;

  // ---- layer 1: x-space aggregation, then 4 head-GEMMs with fused epilogue
  k_cast_attn_x<<<nb4, 256, 0, stream>>>(x, xbf, ws1, wd1, asrc, adst, N);
  k_gather_x<<<nb4, 256, 0, stream>>>(rowStart, csrSrc, ae1, asrc, adst, xbf, aggB, N);
  k_gemm_mfma<128, 128, 64, 64, true, 0><<<dim3(gmM, 1, 4), 256, 0, stream>>>(
      aggB, Wt1, bufA, N, 64, 128, 256, 512, 64, 128 * 64, 128,
      B[0], G[0], BT[0], RM[0], RV[0], nullptr, nullptr, nullptr, nullptr);

  // ---- layer 2: GEMM with fused attn dots (WN=64=C), then gather
  k_gemm_mfma<128, 128, 64, 64, false, 4><<<dim3(gmM, 2, 1), 256, 0, stream>>>(
      bufA, Wt2, bufH, N, 512, 256, 512, 256, 0, 0, 0,
      nullptr, nullptr, nullptr, nullptr, nullptr, AS[1], AD[1], asrc, adst);
  k_gather4<64, 4><<<nb4, 256, 0, stream>>>(rowStart, csrSrc, ae2, asrc, adst,
                                            bufH, B[1], G[1], BT[1], RM[1], RV[1], bufA, N);

  // ---- layer 3: GEMM with fused attn dots (WN=32=C, H=1), then gather
  k_gemm_mfma<128, 32, 32, 32, false, 1><<<dim3(gmM, 1, 1), 256, 0, stream>>>(
      bufA, Wt3, bufH, N, 256, 32, 256, 32, 0, 0, 0,
      nullptr, nullptr, nullptr, nullptr, nullptr, AS[2], AD[2], asrc, adst);
  k_gather_L3<<<nb4, 256, 0, stream>>>(rowStart, csrSrc, ae3buf, asrc, adst,
                                       bufH, B[2], G[2], BT[2], RM[2], RV[2], bufA, N);

  // ---- fused pooling + MLP
  k_pool_mlp<<<NG, 256, 0, stream>>>(bufA, batch, N, lw1, lb1, lw2, lb2, (float*)d_out);
}